// Round 2
// baseline (1983.294 us; speedup 1.0000x reference)
//
#include <hip/hip_runtime.h>
#include <hip/hip_bf16.h>
#include <math.h>

#define N_NODES  8192
#define N_EDGES  49152
#define E_TOT    57344   // edges + self-loops
#define IN_F     128
#define HID      64
#define NH1      64
#define NH2      5
#define OUT_F    32
#define F1       4096    // NH1*HID
#define F2       160     // NH2*OUT_F
#define N_BONDS  64

__device__ __forceinline__ float lrelu(float x){ return x > 0.f ? x : 0.2f*x; }

// ---------------- CSR build (sort edges by dst) ----------------
__global__ void k_init_counts(int* counts){
    int i = blockIdx.x*256 + threadIdx.x;
    if (i < N_NODES) counts[i] = 1;   // self-loop
}
__global__ void k_count(const int* __restrict__ ei, int* counts){
    int i = blockIdx.x*256 + threadIdx.x;
    if (i < N_EDGES) atomicAdd(&counts[ei[N_EDGES + i]], 1);
}
__global__ __launch_bounds__(1024) void k_scan(const int* __restrict__ counts,
                                               int* __restrict__ row_start,
                                               int* __restrict__ cursor){
    __shared__ int sd[1024];
    int t = threadIdx.x;
    int v[8]; int sum = 0;
    #pragma unroll
    for (int i=0;i<8;i++){ v[i] = counts[t*8+i]; sum += v[i]; }
    sd[t] = sum; __syncthreads();
    for (int off=1; off<1024; off<<=1){
        int vv = (t >= off) ? sd[t-off] : 0;
        __syncthreads();
        sd[t] += vv;
        __syncthreads();
    }
    int run = sd[t] - sum;  // exclusive prefix
    #pragma unroll
    for (int i=0;i<8;i++){ row_start[t*8+i] = run; cursor[t*8+i] = run; run += v[i]; }
    if (t == 1023) row_start[N_NODES] = run;
}
__global__ void k_fill(const int* __restrict__ ei, int* cursor, int* __restrict__ csr_src){
    int i = blockIdx.x*256 + threadIdx.x;
    if (i >= E_TOT) return;
    int s, d;
    if (i < N_EDGES){ s = ei[i]; d = ei[N_EDGES + i]; }
    else { s = i - N_EDGES; d = s; }
    int pos = atomicAdd(&cursor[d], 1);
    csr_src[pos] = s;
}

// ---------------- GEMM1 chunk: h1c = x @ Wslice^T  [8192 x ldc], K=128 -------
// block tile 128x128, thread tile 8x8, transposed LDS tiles (k-major)
// grid: (ldc/128, 64). B is pre-offset to the chunk's first row of W1.
__global__ __launch_bounds__(256) void k_gemm1(const float* __restrict__ A,
                                               const float* __restrict__ B,
                                               float* __restrict__ C, int ldc){
    __shared__ float AT[32][132];
    __shared__ float BT[32][132];
    int tx = threadIdx.x, ty = threadIdx.y;
    int tid = ty*16 + tx;
    int m0 = blockIdx.y * 128;
    int n0 = blockIdx.x * 128;
    float acc[8][8] = {};
    int r  = tid >> 1;          // 0..127
    int kq = (tid & 1) * 16;    // 0 or 16
    for (int k0 = 0; k0 < IN_F; k0 += 32){
        #pragma unroll
        for (int q=0;q<4;q++){
            float4 va = *(const float4*)(A + (size_t)(m0 + r)*IN_F + k0 + kq + 4*q);
            float4 vb = *(const float4*)(B + (size_t)(n0 + r)*IN_F + k0 + kq + 4*q);
            int kk = kq + 4*q;
            AT[kk+0][r]=va.x; AT[kk+1][r]=va.y; AT[kk+2][r]=va.z; AT[kk+3][r]=va.w;
            BT[kk+0][r]=vb.x; BT[kk+1][r]=vb.y; BT[kk+2][r]=vb.z; BT[kk+3][r]=vb.w;
        }
        __syncthreads();
        #pragma unroll 4
        for (int k=0;k<32;k++){
            float4 a0 = *(const float4*)&AT[k][ty*8];
            float4 a1 = *(const float4*)&AT[k][ty*8+4];
            float4 b0 = *(const float4*)&BT[k][tx*8];
            float4 b1 = *(const float4*)&BT[k][tx*8+4];
            float aa[8] = {a0.x,a0.y,a0.z,a0.w,a1.x,a1.y,a1.z,a1.w};
            float bb[8] = {b0.x,b0.y,b0.z,b0.w,b1.x,b1.y,b1.z,b1.w};
            #pragma unroll
            for (int i=0;i<8;i++)
                #pragma unroll
                for (int j=0;j<8;j++) acc[i][j] += aa[i]*bb[j];
        }
        __syncthreads();
    }
    #pragma unroll
    for (int i=0;i<8;i++){
        float4 c0 = {acc[i][0],acc[i][1],acc[i][2],acc[i][3]};
        float4 c1 = {acc[i][4],acc[i][5],acc[i][6],acc[i][7]};
        *(float4*)(C + (size_t)(m0+ty*8+i)*ldc + n0 + tx*8    ) = c0;
        *(float4*)(C + (size_t)(m0+ty*8+i)*ldc + n0 + tx*8 + 4) = c1;
    }
}

// ---------------- attention dots, layer-1 chunk ----------------
// block = CF/4 threads; thread t owns 4 features (one float4); 16 threads/head.
// as_w/ad_w are pre-offset att vectors (contiguous CF floats for the chunk).
__global__ __launch_bounds__(1024) void k_alpha1(const float* __restrict__ h1c,
        const float* __restrict__ as_w, const float* __restrict__ ad_w,
        float* __restrict__ asc, float* __restrict__ adc, int CF, int CHc){
    int n = blockIdx.x, t = threadIdx.x;
    float4 h = *(const float4*)(h1c + (size_t)n*CF + t*4);
    float4 a = *(const float4*)(as_w + t*4);
    float4 d = *(const float4*)(ad_w + t*4);
    float ps = h.x*a.x + h.y*a.y + h.z*a.z + h.w*a.w;
    float pd = h.x*d.x + h.y*d.y + h.z*d.z + h.w*d.w;
    ps += __shfl_xor(ps, 1); ps += __shfl_xor(ps, 2);
    ps += __shfl_xor(ps, 4); ps += __shfl_xor(ps, 8);
    pd += __shfl_xor(pd, 1); pd += __shfl_xor(pd, 2);
    pd += __shfl_xor(pd, 4); pd += __shfl_xor(pd, 8);
    if ((t & 15) == 0){
        asc[n*CHc + (t>>4)] = ps;
        adc[n*CHc + (t>>4)] = pd;
    }
}

// ---------------- layer-1 chunk: softmax + aggregation + ELU ----------------
// one block per dst node; softmax shift-invariant -> no segment_max (logits tiny)
__global__ __launch_bounds__(1024) void k_agg1(const float* __restrict__ h1c,
        const float* __restrict__ asc, const float* __restrict__ adc,
        const int* __restrict__ row_start, const int* __restrict__ csr_src,
        const float* __restrict__ b1w, float* __restrict__ x1c, int CF, int CHc){
    int n = blockIdx.x, t = threadIdx.x;
    __shared__ float ad_s[NH1], den_s[NH1];
    int e0 = row_start[n], e1 = row_start[n+1];
    if (t < CHc) ad_s[t] = adc[n*CHc + t];
    __syncthreads();
    if (t < CHc){
        float d = 0.f;
        for (int e=e0;e<e1;e++){
            int s = csr_src[e];
            d += expf(lrelu(asc[s*CHc + t] + ad_s[t]));
        }
        den_s[t] = d;
    }
    __syncthreads();
    int h = t >> 4;
    float adh  = ad_s[h];
    float dinv = 1.f / den_s[h];
    float ax=0.f, ay=0.f, az=0.f, aw=0.f;
    for (int e=e0;e<e1;e++){
        int s = csr_src[e];
        float w = expf(lrelu(asc[s*CHc + h] + adh)) * dinv;
        float4 v = *(const float4*)(h1c + (size_t)s*CF + t*4);
        ax += w*v.x; ay += w*v.y; az += w*v.z; aw += w*v.w;
    }
    float4 b = *(const float4*)(b1w + t*4);
    float v0 = ax + b.x, v1 = ay + b.y, v2 = az + b.z, v3 = aw + b.w;
    float4 o;
    o.x = v0 > 0.f ? v0 : expm1f(v0);
    o.y = v1 > 0.f ? v1 : expm1f(v1);
    o.z = v2 > 0.f ? v2 : expm1f(v2);
    o.w = v3 > 0.f ? v3 : expm1f(v3);
    *(float4*)(x1c + (size_t)n*CF + t*4) = o;
}

// ---------------- zero h2 ----------------
__global__ void k_zero_h2(float4* p){
    p[blockIdx.x*256 + threadIdx.x] = float4{0.f,0.f,0.f,0.f};
}

// ---------------- GEMM2 chunk: h2 += x1c @ Wslice^T, K=CF, k-split 128 -------
// block tile 128x160, thread tile 8x10; grid (64, CF/128); atomics into h2.
// B is pre-offset to the chunk's first column of W2 (row stride stays F1).
__global__ __launch_bounds__(256) void k_gemm2(const float* __restrict__ A,
                                               const float* __restrict__ B,
                                               float* __restrict__ C, int CF){
    __shared__ float AT[32][132];
    __shared__ float BT[32][168];
    int tx = threadIdx.x, ty = threadIdx.y;
    int tid = ty*16 + tx;
    int m0 = blockIdx.x * 128;
    int kbase = blockIdx.y * 128;
    float acc[8][10] = {};
    int r  = tid >> 1;
    int kq = (tid & 1)*16;
    for (int kc = 0; kc < 128; kc += 32){
        int k0 = kbase + kc;
        #pragma unroll
        for (int q=0;q<4;q++){
            float4 va = *(const float4*)(A + (size_t)(m0 + r)*CF + k0 + kq + 4*q);
            int kk = kq + 4*q;
            AT[kk+0][r]=va.x; AT[kk+1][r]=va.y; AT[kk+2][r]=va.z; AT[kk+3][r]=va.w;
        }
        for (int i = tid; i < F2*32; i += 256){
            int nn = i >> 5, kk = i & 31;
            BT[kk][nn] = B[(size_t)nn*F1 + k0 + kk];
        }
        __syncthreads();
        #pragma unroll 4
        for (int k=0;k<32;k++){
            float4 a0 = *(const float4*)&AT[k][ty*8];
            float4 a1 = *(const float4*)&AT[k][ty*8+4];
            float aa[8] = {a0.x,a0.y,a0.z,a0.w,a1.x,a1.y,a1.z,a1.w};
            float bb[10];
            #pragma unroll
            for (int j=0;j<5;j++){
                float2 bv = *(const float2*)&BT[k][tx*10 + 2*j];
                bb[2*j] = bv.x; bb[2*j+1] = bv.y;
            }
            #pragma unroll
            for (int i=0;i<8;i++)
                #pragma unroll
                for (int j=0;j<10;j++) acc[i][j] += aa[i]*bb[j];
        }
        __syncthreads();
    }
    #pragma unroll
    for (int i=0;i<8;i++)
        #pragma unroll
        for (int j=0;j<10;j++)
            atomicAdd(&C[(size_t)(m0+ty*8+i)*F2 + tx*10 + j], acc[i][j]);
}

// ---------------- attention dots, layer 2 ----------------
__global__ __launch_bounds__(64) void k_alpha2(const float* __restrict__ h2,
        const float* __restrict__ att_s, const float* __restrict__ att_d,
        float* __restrict__ as2, float* __restrict__ ad2){
    int n = blockIdx.x, t = threadIdx.x;
    float ps = 0.f, pd = 0.f;
    if (t < 40){
        float4 h = *(const float4*)(h2 + (size_t)n*F2 + t*4);
        float4 a = ((const float4*)att_s)[t];
        float4 d = ((const float4*)att_d)[t];
        ps = h.x*a.x + h.y*a.y + h.z*a.z + h.w*a.w;
        pd = h.x*d.x + h.y*d.y + h.z*d.z + h.w*d.w;
    }
    ps += __shfl_xor(ps,1); ps += __shfl_xor(ps,2); ps += __shfl_xor(ps,4);
    pd += __shfl_xor(pd,1); pd += __shfl_xor(pd,2); pd += __shfl_xor(pd,4);
    if (t < 40 && (t & 7) == 0){
        as2[n*NH2 + (t>>3)] = ps;
        ad2[n*NH2 + (t>>3)] = pd;
    }
}

// ---------------- layer-2 softmax + aggregation + head-mean + b2 ----------------
__global__ __launch_bounds__(256) void k_agg2(const float* __restrict__ h2,
        const float* __restrict__ as2, const float* __restrict__ ad2,
        const int* __restrict__ row_start, const int* __restrict__ csr_src,
        const float* __restrict__ b2, float* __restrict__ x2){
    int n = blockIdx.x, t = threadIdx.x;
    __shared__ float ad_s[NH2], den_s[NH2], sacc[F2];
    int e0 = row_start[n], e1 = row_start[n+1];
    if (t < NH2) ad_s[t] = ad2[n*NH2 + t];
    __syncthreads();
    if (t < NH2){
        float d = 0.f;
        for (int e=e0;e<e1;e++){
            int s = csr_src[e];
            d += expf(lrelu(as2[s*NH2 + t] + ad_s[t]));
        }
        den_s[t] = d;
    }
    __syncthreads();
    if (t < F2){
        int h = t >> 5;
        float adh  = ad_s[h];
        float dinv = 1.f/den_s[h];
        float acc = 0.f;
        for (int e=e0;e<e1;e++){
            int s = csr_src[e];
            float w = expf(lrelu(as2[s*NH2 + h] + adh)) * dinv;
            acc += w * h2[(size_t)s*F2 + t];
        }
        sacc[t] = acc;
    }
    __syncthreads();
    if (t < OUT_F){
        float v = (sacc[t] + sacc[t+32] + sacc[t+64] + sacc[t+96] + sacc[t+128]) * 0.2f + b2[t];
        x2[n*OUT_F + t] = v;
    }
}

// ---------------- bond scores + softmax over 64 bonds ----------------
__global__ __launch_bounds__(64) void k_bond(const float* __restrict__ x2,
        const int* __restrict__ lefts, const int* __restrict__ rights,
        float* __restrict__ out){
    int b = threadIdx.x;
    int L = lefts[b], R = rights[b];
    float s = 0.f;
    #pragma unroll
    for (int c=0;c<OUT_F;c+=4){
        float4 l4 = *(const float4*)(x2 + (size_t)L*OUT_F + c);
        float4 r4 = *(const float4*)(x2 + (size_t)R*OUT_F + c);
        s += l4.x+l4.y+l4.z+l4.w + r4.x+r4.y+r4.z+r4.w;
    }
    float m = s;
    #pragma unroll
    for (int off=1; off<64; off<<=1) m = fmaxf(m, __shfl_xor(m, off));
    float e = expf(s - m);
    float sum = e;
    #pragma unroll
    for (int off=1; off<64; off<<=1) sum += __shfl_xor(sum, off);
    out[b] = e / sum;
}

extern "C" void kernel_launch(void* const* d_in, const int* in_sizes, int n_in,
                              void* d_out, int out_size, void* d_ws, size_t ws_size,
                              hipStream_t stream){
    const float* x      = (const float*)d_in[0];
    const int*   ei     = (const int*)  d_in[1];
    const int*   lefts  = (const int*)  d_in[2];
    const int*   rights = (const int*)  d_in[3];
    const float* W1     = (const float*)d_in[4];
    const float* att_s1 = (const float*)d_in[5];
    const float* att_d1 = (const float*)d_in[6];
    const float* b1     = (const float*)d_in[7];
    const float* W2     = (const float*)d_in[8];
    const float* att_s2 = (const float*)d_in[9];
    const float* att_d2 = (const float*)d_in[10];
    const float* b2     = (const float*)d_in[11];
    float* out = (float*)d_out;

    // ---- choose chunk width from ws_size (constant across calls) ----
    // fixed buffers: h2 + as2/ad2 + x2 + CSR + alignment slack
    size_t fixed = (size_t)(N_NODES*F2 + 2*N_NODES*NH2 + N_NODES*OUT_F
                          + N_NODES + (N_NODES+1) + N_NODES + E_TOT) * 4 + 8192;
    int CF = 256;  // minimum fallback
    const int cands[4] = {4096, 2048, 1024, 512};
    for (int c = 0; c < 4; c++){
        size_t need = fixed + (size_t)N_NODES * cands[c] * 4 * 2        // h1c + x1c
                            + (size_t)N_NODES * (cands[c]/HID) * 4 * 2; // asc + adc
        if (need <= ws_size){ CF = cands[c]; break; }
    }
    const int CHc = CF / HID;       // heads per chunk
    const int NCHUNK = F1 / CF;

    char* ws = (char*)d_ws;
    size_t off = 0;
    auto alloc = [&](size_t bytes) -> void* {
        void* p = ws + off;
        off += (bytes + 255) & ~(size_t)255;
        return p;
    };
    float* h1c  = (float*)alloc((size_t)N_NODES*CF*4);
    float* x1c  = (float*)alloc((size_t)N_NODES*CF*4);
    float* h2   = (float*)alloc((size_t)N_NODES*F2*4);
    float* asc  = (float*)alloc((size_t)N_NODES*CHc*4);
    float* adc  = (float*)alloc((size_t)N_NODES*CHc*4);
    float* as2  = (float*)alloc((size_t)N_NODES*NH2*4);
    float* ad2  = (float*)alloc((size_t)N_NODES*NH2*4);
    float* x2   = (float*)alloc((size_t)N_NODES*OUT_F*4);
    int* counts    = (int*)alloc((size_t)N_NODES*4);
    int* row_start = (int*)alloc((size_t)(N_NODES+1)*4);
    int* cursor    = (int*)alloc((size_t)N_NODES*4);
    int* csr_src   = (int*)alloc((size_t)E_TOT*4);

    k_init_counts<<<32, 256, 0, stream>>>(counts);
    k_count<<<192, 256, 0, stream>>>(ei, counts);
    k_scan<<<1, 1024, 0, stream>>>(counts, row_start, cursor);
    k_fill<<<224, 256, 0, stream>>>(ei, cursor, csr_src);

    k_zero_h2<<<1280, 256, 0, stream>>>((float4*)h2);

    for (int c = 0; c < NCHUNK; c++){
        int cb = c * CF;  // feature/column base of this chunk
        k_gemm1<<<dim3(CF/128, 64), dim3(16,16), 0, stream>>>(
            x, W1 + (size_t)cb*IN_F, h1c, CF);
        k_alpha1<<<N_NODES, CF/4, 0, stream>>>(
            h1c, att_s1 + cb, att_d1 + cb, asc, adc, CF, CHc);
        k_agg1<<<N_NODES, CF/4, 0, stream>>>(
            h1c, asc, adc, row_start, csr_src, b1 + cb, x1c, CF, CHc);
        k_gemm2<<<dim3(64, CF/128), dim3(16,16), 0, stream>>>(
            x1c, W2 + cb, h2, CF);
    }

    k_alpha2<<<N_NODES, 64, 0, stream>>>(h2, att_s2, att_d2, as2, ad2);
    k_agg2<<<N_NODES, 256, 0, stream>>>(h2, as2, ad2, row_start, csr_src, b2, x2);

    k_bond<<<1, 64, 0, stream>>>(x2, lefts, rights, out);
}

// Round 4
// 1247.440 us; speedup vs baseline: 1.5899x; 1.5899x over previous
//
#include <hip/hip_runtime.h>
#include <hip/hip_bf16.h>
#include <math.h>

#define N_NODES  8192
#define N_EDGES  49152
#define E_TOT    57344   // edges + self-loops
#define IN_F     128
#define HID      64
#define NH1      64
#define NH2      5
#define OUT_F    32
#define F1       4096    // NH1*HID
#define F2       160     // NH2*OUT_F
#define N_BONDS  64
#define ET       8       // agg1 edge-tile

__device__ __forceinline__ float lrelu(float x){ return x > 0.f ? x : 0.2f*x; }

// ---------------- CSR build (sort edges by dst) ----------------
__global__ void k_init_counts(int* counts){
    int i = blockIdx.x*256 + threadIdx.x;
    if (i < N_NODES) counts[i] = 1;   // self-loop
}
__global__ void k_count(const int* __restrict__ ei, int* counts){
    int i = blockIdx.x*256 + threadIdx.x;
    if (i < N_EDGES) atomicAdd(&counts[ei[N_EDGES + i]], 1);
}
__global__ __launch_bounds__(1024) void k_scan(const int* __restrict__ counts,
                                               int* __restrict__ row_start,
                                               int* __restrict__ cursor){
    __shared__ int sd[1024];
    int t = threadIdx.x;
    int v[8]; int sum = 0;
    #pragma unroll
    for (int i=0;i<8;i++){ v[i] = counts[t*8+i]; sum += v[i]; }
    sd[t] = sum; __syncthreads();
    for (int off=1; off<1024; off<<=1){
        int vv = (t >= off) ? sd[t-off] : 0;
        __syncthreads();
        sd[t] += vv;
        __syncthreads();
    }
    int run = sd[t] - sum;  // exclusive prefix
    #pragma unroll
    for (int i=0;i<8;i++){ row_start[t*8+i] = run; cursor[t*8+i] = run; run += v[i]; }
    if (t == 1023) row_start[N_NODES] = run;
}
__global__ void k_fill(const int* __restrict__ ei, int* cursor, int* __restrict__ csr_src){
    int i = blockIdx.x*256 + threadIdx.x;
    if (i >= E_TOT) return;
    int s, d;
    if (i < N_EDGES){ s = ei[i]; d = ei[N_EDGES + i]; }
    else { s = i - N_EDGES; d = s; }
    int pos = atomicAdd(&cursor[d], 1);
    csr_src[pos] = s;
}

// ------- attention vectors: vsT[k][h] = sum_c a_s[h,c] * W1[h*64+c, k] -------
__global__ __launch_bounds__(128) void k_attvec(const float* __restrict__ W1,
        const float* __restrict__ a_s, const float* __restrict__ a_d,
        float* __restrict__ vsT, float* __restrict__ vdT){
    int h = blockIdx.x, k = threadIdx.x;
    float s = 0.f, d = 0.f;
    for (int c = 0; c < HID; c++){
        float w = W1[(size_t)(h*HID + c)*IN_F + k];   // 128 lanes: coalesced
        s += a_s[h*HID + c] * w;
        d += a_d[h*HID + c] * w;
    }
    vsT[k*NH1 + h] = s;
    vdT[k*NH1 + h] = d;
}

// ---------- alpha dots from x: as1[n,h] = x[n,:] . vsT[:,h] ------------------
__global__ __launch_bounds__(128) void k_alpha1x(const float* __restrict__ x,
        const float* __restrict__ vsT, const float* __restrict__ vdT,
        float* __restrict__ as1, float* __restrict__ ad1){
    int n = blockIdx.x, t = threadIdx.x;
    __shared__ float xs[IN_F];
    xs[t] = x[(size_t)n*IN_F + t];
    __syncthreads();
    if (t < NH1){
        float s = 0.f, d = 0.f;
        for (int k = 0; k < IN_F; k++){
            float xv = xs[k];
            s += xv * vsT[k*NH1 + t];   // 64 lanes consecutive: coalesced, L1-hot
            d += xv * vdT[k*NH1 + t];
        }
        as1[n*NH1 + t] = s;
        ad1[n*NH1 + t] = d;
    }
}

// ---------- per-node per-head softmax denominators (once, all 64 heads) ------
__global__ __launch_bounds__(64) void k_dinv(const float* __restrict__ as1,
        const float* __restrict__ ad1, const int* __restrict__ row_start,
        const int* __restrict__ csr_src, float* __restrict__ dinv){
    int n = blockIdx.x, h = threadIdx.x;
    float ad = ad1[n*NH1 + h];
    int e0 = row_start[n], e1 = row_start[n+1];
    float d = 0.f;
    for (int e = e0; e < e1; e++){
        int s = csr_src[e];
        d += expf(lrelu(as1[s*NH1 + h] + ad));   // 64 lanes: coalesced 256B row
    }
    dinv[n*NH1 + h] = 1.f / d;
}

// ------- GEMM1 chunk: h1c = x @ Wslice^T  [8192 x CF], K=128 -----------------
// block tile 128x128, thread tile 8x8, transposed LDS tiles (k-major)
// grid: (CF/128, 64). B pre-offset to chunk's first row of W1.
__global__ __launch_bounds__(256) void k_gemm1(const float* __restrict__ A,
                                               const float* __restrict__ B,
                                               float* __restrict__ C, int ldc){
    __shared__ float AT[32][132];
    __shared__ float BT[32][132];
    int tx = threadIdx.x, ty = threadIdx.y;
    int tid = ty*16 + tx;
    int m0 = blockIdx.y * 128;
    int n0 = blockIdx.x * 128;
    float acc[8][8] = {};
    int r  = tid >> 1;          // 0..127
    int kq = (tid & 1) * 16;    // 0 or 16
    for (int k0 = 0; k0 < IN_F; k0 += 32){
        #pragma unroll
        for (int q=0;q<4;q++){
            float4 va = *(const float4*)(A + (size_t)(m0 + r)*IN_F + k0 + kq + 4*q);
            float4 vb = *(const float4*)(B + (size_t)(n0 + r)*IN_F + k0 + kq + 4*q);
            int kk = kq + 4*q;
            AT[kk+0][r]=va.x; AT[kk+1][r]=va.y; AT[kk+2][r]=va.z; AT[kk+3][r]=va.w;
            BT[kk+0][r]=vb.x; BT[kk+1][r]=vb.y; BT[kk+2][r]=vb.z; BT[kk+3][r]=vb.w;
        }
        __syncthreads();
        #pragma unroll 4
        for (int k=0;k<32;k++){
            float4 a0 = *(const float4*)&AT[k][ty*8];
            float4 a1 = *(const float4*)&AT[k][ty*8+4];
            float4 b0 = *(const float4*)&BT[k][tx*8];
            float4 b1 = *(const float4*)&BT[k][tx*8+4];
            float aa[8] = {a0.x,a0.y,a0.z,a0.w,a1.x,a1.y,a1.z,a1.w};
            float bb[8] = {b0.x,b0.y,b0.z,b0.w,b1.x,b1.y,b1.z,b1.w};
            #pragma unroll
            for (int i=0;i<8;i++)
                #pragma unroll
                for (int j=0;j<8;j++) acc[i][j] += aa[i]*bb[j];
        }
        __syncthreads();
    }
    #pragma unroll
    for (int i=0;i<8;i++){
        float4 c0 = {acc[i][0],acc[i][1],acc[i][2],acc[i][3]};
        float4 c1 = {acc[i][4],acc[i][5],acc[i][6],acc[i][7]};
        *(float4*)(C + (size_t)(m0+ty*8+i)*ldc + n0 + tx*8    ) = c0;
        *(float4*)(C + (size_t)(m0+ty*8+i)*ldc + n0 + tx*8 + 4) = c1;
    }
}

// ------- layer-1 chunk: softmax-weighted aggregation + bias + ELU ------------
// one block per dst node, CF/8 threads, 8 feats/thread, head = t>>3.
// weights computed once per (edge, chunk-head) into LDS tile; dinv precomputed.
__global__ __launch_bounds__(512) void k_agg1(const float* __restrict__ h1c,
        const float* __restrict__ as1, const float* __restrict__ ad1,
        const float* __restrict__ dinv,
        const int* __restrict__ row_start, const int* __restrict__ csr_src,
        const float* __restrict__ b1w, float* __restrict__ x1c,
        int CF, int h0, int chs){
    int n = blockIdx.x, t = threadIdx.x;
    int CHc = 1 << chs;
    __shared__ float ad_s[NH1], dv_s[NH1];
    __shared__ float wt[ET][NH1];
    __shared__ int   st[ET];
    int e0 = row_start[n], e1 = row_start[n+1];
    if (t < CHc){
        ad_s[t] = ad1[n*NH1 + h0 + t];
        dv_s[t] = dinv[n*NH1 + h0 + t];
    }
    __syncthreads();
    int hl = t >> 3;   // chunk-local head of this thread's 8 features
    float acc[8] = {};
    for (int eb = e0; eb < e1; eb += ET){
        int ne = min(ET, e1 - eb);
        for (int idx = t; idx < ne*CHc; idx += blockDim.x){
            int el = idx >> chs, hh = idx & (CHc-1);
            int s = csr_src[eb + el];
            if (hh == 0) st[el] = s;
            wt[el][hh] = expf(lrelu(as1[s*NH1 + h0 + hh] + ad_s[hh])) * dv_s[hh];
        }
        __syncthreads();
        for (int e = 0; e < ne; e++){
            int s = st[e];
            float w = wt[e][hl];
            float4 v0 = *(const float4*)(h1c + (size_t)s*CF + t*8);
            float4 v1 = *(const float4*)(h1c + (size_t)s*CF + t*8 + 4);
            acc[0] += w*v0.x; acc[1] += w*v0.y; acc[2] += w*v0.z; acc[3] += w*v0.w;
            acc[4] += w*v1.x; acc[5] += w*v1.y; acc[6] += w*v1.z; acc[7] += w*v1.w;
        }
        __syncthreads();
    }
    float4 b0 = *(const float4*)(b1w + t*8);
    float4 b1 = *(const float4*)(b1w + t*8 + 4);
    float v[8] = {acc[0]+b0.x, acc[1]+b0.y, acc[2]+b0.z, acc[3]+b0.w,
                  acc[4]+b1.x, acc[5]+b1.y, acc[6]+b1.z, acc[7]+b1.w};
    float o[8];
    #pragma unroll
    for (int i=0;i<8;i++) o[i] = v[i] > 0.f ? v[i] : expm1f(v[i]);
    *(float4*)(x1c + (size_t)n*CF + t*8    ) = float4{o[0],o[1],o[2],o[3]};
    *(float4*)(x1c + (size_t)n*CF + t*8 + 4) = float4{o[4],o[5],o[6],o[7]};
}

// ---------------- zero h2 ----------------
__global__ void k_zero_h2(float4* p){
    p[blockIdx.x*256 + threadIdx.x] = float4{0.f,0.f,0.f,0.f};
}

// ------- GEMM2 chunk: h2 += x1c @ Wslice^T, K=CF -----------------------------
// grid 256 blocks; each owns a 32-row m-tile and ALL of chunk-K in registers.
// No atomics: read-modify-write (unique ownership). B pre-offset by chunk col.
__global__ __launch_bounds__(256) void k_gemm2(const float* __restrict__ A,
                                               const float* __restrict__ B,
                                               float* __restrict__ h2, int CF){
    __shared__ float AT[32][33];
    __shared__ float BT[32][168];
    int tid = threadIdx.x;
    int tx = tid & 15, ty = tid >> 4;
    int m0 = blockIdx.x * 32;
    float acc[2][10] = {};
    int r = tid >> 3, q = tid & 7;   // A stage: row r (0..31), quad q (0..7)
    for (int k0 = 0; k0 < CF; k0 += 32){
        float4 va = *(const float4*)(A + (size_t)(m0 + r)*CF + k0 + q*4);
        AT[q*4+0][r]=va.x; AT[q*4+1][r]=va.y; AT[q*4+2][r]=va.z; AT[q*4+3][r]=va.w;
        for (int i = tid; i < F2*32; i += 256){
            int nn = i >> 5, kk = i & 31;
            BT[kk][nn] = B[(size_t)nn*F1 + k0 + kk];
        }
        __syncthreads();
        #pragma unroll 8
        for (int k=0;k<32;k++){
            float a0 = AT[k][ty*2], a1 = AT[k][ty*2+1];
            float bb[10];
            #pragma unroll
            for (int j=0;j<5;j++){
                float2 bv = *(const float2*)&BT[k][tx*10 + 2*j];
                bb[2*j] = bv.x; bb[2*j+1] = bv.y;
            }
            #pragma unroll
            for (int j=0;j<10;j++){
                acc[0][j] += a0*bb[j];
                acc[1][j] += a1*bb[j];
            }
        }
        __syncthreads();
    }
    #pragma unroll
    for (int i=0;i<2;i++){
        float* row = h2 + (size_t)(m0 + ty*2 + i)*F2 + tx*10;
        #pragma unroll
        for (int j=0;j<5;j++){
            float2 o = *(float2*)(row + 2*j);
            o.x += acc[i][2*j]; o.y += acc[i][2*j+1];
            *(float2*)(row + 2*j) = o;
        }
    }
}

// ---------------- attention dots, layer 2 ----------------
__global__ __launch_bounds__(64) void k_alpha2(const float* __restrict__ h2,
        const float* __restrict__ att_s, const float* __restrict__ att_d,
        float* __restrict__ as2, float* __restrict__ ad2){
    int n = blockIdx.x, t = threadIdx.x;
    float ps = 0.f, pd = 0.f;
    if (t < 40){
        float4 h = *(const float4*)(h2 + (size_t)n*F2 + t*4);
        float4 a = ((const float4*)att_s)[t];
        float4 d = ((const float4*)att_d)[t];
        ps = h.x*a.x + h.y*a.y + h.z*a.z + h.w*a.w;
        pd = h.x*d.x + h.y*d.y + h.z*d.z + h.w*d.w;
    }
    ps += __shfl_xor(ps,1); ps += __shfl_xor(ps,2); ps += __shfl_xor(ps,4);
    pd += __shfl_xor(pd,1); pd += __shfl_xor(pd,2); pd += __shfl_xor(pd,4);
    if (t < 40 && (t & 7) == 0){
        as2[n*NH2 + (t>>3)] = ps;
        ad2[n*NH2 + (t>>3)] = pd;
    }
}

// ------- layer-2 softmax + aggregation + head-mean + b2 ----------------------
__global__ __launch_bounds__(256) void k_agg2(const float* __restrict__ h2,
        const float* __restrict__ as2, const float* __restrict__ ad2,
        const int* __restrict__ row_start, const int* __restrict__ csr_src,
        const float* __restrict__ b2, float* __restrict__ x2){
    int n = blockIdx.x, t = threadIdx.x;
    __shared__ float ad_s[NH2], den_s[NH2], sacc[F2];
    int e0 = row_start[n], e1 = row_start[n+1];
    if (t < NH2) ad_s[t] = ad2[n*NH2 + t];
    __syncthreads();
    if (t < NH2){
        float d = 0.f;
        for (int e=e0;e<e1;e++){
            int s = csr_src[e];
            d += expf(lrelu(as2[s*NH2 + t] + ad_s[t]));
        }
        den_s[t] = d;
    }
    __syncthreads();
    if (t < F2){
        int h = t >> 5;
        float adh  = ad_s[h];
        float dinv = 1.f/den_s[h];
        float acc = 0.f;
        for (int e=e0;e<e1;e++){
            int s = csr_src[e];
            float w = expf(lrelu(as2[s*NH2 + h] + adh)) * dinv;
            acc += w * h2[(size_t)s*F2 + t];
        }
        sacc[t] = acc;
    }
    __syncthreads();
    if (t < OUT_F){
        float v = (sacc[t] + sacc[t+32] + sacc[t+64] + sacc[t+96] + sacc[t+128]) * 0.2f + b2[t];
        x2[n*OUT_F + t] = v;
    }
}

// ---------------- bond scores + softmax over 64 bonds ----------------
__global__ __launch_bounds__(64) void k_bond(const float* __restrict__ x2,
        const int* __restrict__ lefts, const int* __restrict__ rights,
        float* __restrict__ out){
    int b = threadIdx.x;
    int L = lefts[b], R = rights[b];
    float s = 0.f;
    #pragma unroll
    for (int c=0;c<OUT_F;c+=4){
        float4 l4 = *(const float4*)(x2 + (size_t)L*OUT_F + c);
        float4 r4 = *(const float4*)(x2 + (size_t)R*OUT_F + c);
        s += l4.x+l4.y+l4.z+l4.w + r4.x+r4.y+r4.z+r4.w;
    }
    float m = s;
    #pragma unroll
    for (int off=1; off<64; off<<=1) m = fmaxf(m, __shfl_xor(m, off));
    float e = expf(s - m);
    float sum = e;
    #pragma unroll
    for (int off=1; off<64; off<<=1) sum += __shfl_xor(sum, off);
    out[b] = e / sum;
}

extern "C" void kernel_launch(void* const* d_in, const int* in_sizes, int n_in,
                              void* d_out, int out_size, void* d_ws, size_t ws_size,
                              hipStream_t stream){
    const float* x      = (const float*)d_in[0];
    const int*   ei     = (const int*)  d_in[1];
    const int*   lefts  = (const int*)  d_in[2];
    const int*   rights = (const int*)  d_in[3];
    const float* W1     = (const float*)d_in[4];
    const float* att_s1 = (const float*)d_in[5];
    const float* att_d1 = (const float*)d_in[6];
    const float* b1     = (const float*)d_in[7];
    const float* W2     = (const float*)d_in[8];
    const float* att_s2 = (const float*)d_in[9];
    const float* att_d2 = (const float*)d_in[10];
    const float* b2     = (const float*)d_in[11];
    float* out = (float*)d_out;

    // ---- choose chunk width from ws_size (same every call) ----
    // fixed: h2 + as1/ad1/dinv + as2/ad2 + x2 + vsT/vdT + CSR ints + slack
    size_t fixed = (size_t)(N_NODES*F2 + 3*N_NODES*NH1 + 2*N_NODES*NH2
                          + N_NODES*OUT_F + 2*IN_F*NH1
                          + 3*N_NODES + 1 + E_TOT) * 4 + 16384;
    int CF = 512;
    const int cands[3] = {4096, 2048, 1024};
    for (int c = 0; c < 3; c++){
        size_t need = fixed + (size_t)N_NODES * cands[c] * 4 * 2;  // h1c + x1c
        if (need <= ws_size){ CF = cands[c]; break; }
    }
    const int NCHUNK = F1 / CF;
    int chs = 0; while ((1 << chs) < CF/HID) chs++;   // log2(heads per chunk)

    char* ws = (char*)d_ws;
    size_t off = 0;
    auto alloc = [&](size_t bytes) -> void* {
        void* p = ws + off;
        off += (bytes + 255) & ~(size_t)255;
        return p;
    };
    float* h1c  = (float*)alloc((size_t)N_NODES*CF*4);
    float* x1c  = (float*)alloc((size_t)N_NODES*CF*4);
    float* h2   = (float*)alloc((size_t)N_NODES*F2*4);
    float* as1  = (float*)alloc((size_t)N_NODES*NH1*4);
    float* ad1  = (float*)alloc((size_t)N_NODES*NH1*4);
    float* dinv = (float*)alloc((size_t)N_NODES*NH1*4);
    float* as2  = (float*)alloc((size_t)N_NODES*NH2*4);
    float* ad2  = (float*)alloc((size_t)N_NODES*NH2*4);
    float* x2   = (float*)alloc((size_t)N_NODES*OUT_F*4);
    float* vsT  = (float*)alloc((size_t)IN_F*NH1*4);
    float* vdT  = (float*)alloc((size_t)IN_F*NH1*4);
    int* counts    = (int*)alloc((size_t)N_NODES*4);
    int* row_start = (int*)alloc((size_t)(N_NODES+1)*4);
    int* cursor    = (int*)alloc((size_t)N_NODES*4);
    int* csr_src   = (int*)alloc((size_t)E_TOT*4);

    // CSR by destination
    k_init_counts<<<32, 256, 0, stream>>>(counts);
    k_count<<<192, 256, 0, stream>>>(ei, counts);
    k_scan<<<1, 1024, 0, stream>>>(counts, row_start, cursor);
    k_fill<<<224, 256, 0, stream>>>(ei, cursor, csr_src);

    // alpha dots + denominators (once, from x — no h1 re-read)
    k_attvec<<<NH1, 128, 0, stream>>>(W1, att_s1, att_d1, vsT, vdT);
    k_alpha1x<<<N_NODES, 128, 0, stream>>>(x, vsT, vdT, as1, ad1);
    k_dinv<<<N_NODES, 64, 0, stream>>>(as1, ad1, row_start, csr_src, dinv);

    k_zero_h2<<<N_NODES*F2/4/256, 256, 0, stream>>>((float4*)h2);

    for (int c = 0; c < NCHUNK; c++){
        int cb = c * CF;          // feature/column base
        int h0 = cb / HID;        // first head of chunk
        k_gemm1<<<dim3(CF/128, 64), dim3(16,16), 0, stream>>>(
            x, W1 + (size_t)cb*IN_F, h1c, CF);
        k_agg1<<<N_NODES, CF/8, 0, stream>>>(
            h1c, as1, ad1, dinv, row_start, csr_src, b1 + cb, x1c, CF, h0, chs);
        k_gemm2<<<256, 256, 0, stream>>>(x1c, W2 + cb, h2, CF);
    }

    k_alpha2<<<N_NODES, 64, 0, stream>>>(h2, att_s2, att_d2, as2, ad2);
    k_agg2<<<N_NODES, 256, 0, stream>>>(h2, as2, ad2, row_start, csr_src, b2, x2);

    k_bond<<<1, 64, 0, stream>>>(x2, lefts, rights, out);
}

// Round 5
// 675.202 us; speedup vs baseline: 2.9373x; 1.8475x over previous
//
#include <hip/hip_runtime.h>
#include <hip/hip_bf16.h>
#include <math.h>

#define N_NODES  8192
#define N_EDGES  49152
#define E_TOT    57344   // edges + self-loops
#define IN_F     128
#define HID      64
#define NH1      64
#define NH2      5
#define OUT_F    32
#define F1       4096    // NH1*HID
#define F2       160     // NH2*OUT_F
#define N_BONDS  64
#define ET       8       // agg1 edge-tile
#define KS2      4       // gemm2 k-split (partial buffers)

__device__ __forceinline__ float lrelu(float x){ return x > 0.f ? x : 0.2f*x; }

// ---------------- CSR build (sort edges by dst) ----------------
__global__ void k_init_counts(int* counts){
    int i = blockIdx.x*256 + threadIdx.x;
    if (i < N_NODES) counts[i] = 1;   // self-loop
}
__global__ void k_count(const int* __restrict__ ei, int* counts){
    int i = blockIdx.x*256 + threadIdx.x;
    if (i < N_EDGES) atomicAdd(&counts[ei[N_EDGES + i]], 1);
}
__global__ __launch_bounds__(1024) void k_scan(const int* __restrict__ counts,
                                               int* __restrict__ row_start,
                                               int* __restrict__ cursor){
    __shared__ int sd[1024];
    int t = threadIdx.x;
    int v[8]; int sum = 0;
    #pragma unroll
    for (int i=0;i<8;i++){ v[i] = counts[t*8+i]; sum += v[i]; }
    sd[t] = sum; __syncthreads();
    for (int off=1; off<1024; off<<=1){
        int vv = (t >= off) ? sd[t-off] : 0;
        __syncthreads();
        sd[t] += vv;
        __syncthreads();
    }
    int run = sd[t] - sum;  // exclusive prefix
    #pragma unroll
    for (int i=0;i<8;i++){ row_start[t*8+i] = run; cursor[t*8+i] = run; run += v[i]; }
    if (t == 1023) row_start[N_NODES] = run;
}
__global__ void k_fill(const int* __restrict__ ei, int* cursor, int* __restrict__ csr_src){
    int i = blockIdx.x*256 + threadIdx.x;
    if (i >= E_TOT) return;
    int s, d;
    if (i < N_EDGES){ s = ei[i]; d = ei[N_EDGES + i]; }
    else { s = i - N_EDGES; d = s; }
    int pos = atomicAdd(&cursor[d], 1);
    csr_src[pos] = s;
}

// ------- attention vectors: vsT[k][h] = sum_c a_s[h,c] * W1[h*64+c, k] -------
__global__ __launch_bounds__(128) void k_attvec(const float* __restrict__ W1,
        const float* __restrict__ a_s, const float* __restrict__ a_d,
        float* __restrict__ vsT, float* __restrict__ vdT){
    int h = blockIdx.x, k = threadIdx.x;
    float s = 0.f, d = 0.f;
    for (int c = 0; c < HID; c++){
        float w = W1[(size_t)(h*HID + c)*IN_F + k];   // 128 lanes: coalesced
        s += a_s[h*HID + c] * w;
        d += a_d[h*HID + c] * w;
    }
    vsT[k*NH1 + h] = s;
    vdT[k*NH1 + h] = d;
}

// ---------- alpha dots from x: as1[n,h] = x[n,:] . vsT[:,h] ------------------
__global__ __launch_bounds__(128) void k_alpha1x(const float* __restrict__ x,
        const float* __restrict__ vsT, const float* __restrict__ vdT,
        float* __restrict__ as1, float* __restrict__ ad1){
    int n = blockIdx.x, t = threadIdx.x;
    __shared__ float xs[IN_F];
    xs[t] = x[(size_t)n*IN_F + t];
    __syncthreads();
    if (t < NH1){
        float s = 0.f, d = 0.f;
        for (int k = 0; k < IN_F; k++){
            float xv = xs[k];
            s += xv * vsT[k*NH1 + t];   // 64 lanes consecutive: coalesced, L1-hot
            d += xv * vdT[k*NH1 + t];
        }
        as1[n*NH1 + t] = s;
        ad1[n*NH1 + t] = d;
    }
}

// ---------- per-node per-head softmax denominators (once, all 64 heads) ------
__global__ __launch_bounds__(64) void k_dinv(const float* __restrict__ as1,
        const float* __restrict__ ad1, const int* __restrict__ row_start,
        const int* __restrict__ csr_src, float* __restrict__ dinv){
    int n = blockIdx.x, h = threadIdx.x;
    float ad = ad1[n*NH1 + h];
    int e0 = row_start[n], e1 = row_start[n+1];
    float d = 0.f;
    for (int e = e0; e < e1; e++){
        int s = csr_src[e];
        d += expf(lrelu(as1[s*NH1 + h] + ad));   // 64 lanes: coalesced 256B row
    }
    dinv[n*NH1 + h] = 1.f / d;
}

// ------- GEMM1 chunk: h1c = x @ Wslice^T  [8192 x CF], K=128 -----------------
// block tile 128x128, thread tile 8x8, transposed LDS tiles (k-major)
// grid: (CF/128, 64). B pre-offset to chunk's first row of W1.
__global__ __launch_bounds__(256) void k_gemm1(const float* __restrict__ A,
                                               const float* __restrict__ B,
                                               float* __restrict__ C, int ldc){
    __shared__ float AT[32][132];
    __shared__ float BT[32][132];
    int tx = threadIdx.x, ty = threadIdx.y;
    int tid = ty*16 + tx;
    int m0 = blockIdx.y * 128;
    int n0 = blockIdx.x * 128;
    float acc[8][8] = {};
    int r  = tid >> 1;          // 0..127
    int kq = (tid & 1) * 16;    // 0 or 16
    for (int k0 = 0; k0 < IN_F; k0 += 32){
        #pragma unroll
        for (int q=0;q<4;q++){
            float4 va = *(const float4*)(A + (size_t)(m0 + r)*IN_F + k0 + kq + 4*q);
            float4 vb = *(const float4*)(B + (size_t)(n0 + r)*IN_F + k0 + kq + 4*q);
            int kk = kq + 4*q;
            AT[kk+0][r]=va.x; AT[kk+1][r]=va.y; AT[kk+2][r]=va.z; AT[kk+3][r]=va.w;
            BT[kk+0][r]=vb.x; BT[kk+1][r]=vb.y; BT[kk+2][r]=vb.z; BT[kk+3][r]=vb.w;
        }
        __syncthreads();
        #pragma unroll 4
        for (int k=0;k<32;k++){
            float4 a0 = *(const float4*)&AT[k][ty*8];
            float4 a1 = *(const float4*)&AT[k][ty*8+4];
            float4 b0 = *(const float4*)&BT[k][tx*8];
            float4 b1 = *(const float4*)&BT[k][tx*8+4];
            float aa[8] = {a0.x,a0.y,a0.z,a0.w,a1.x,a1.y,a1.z,a1.w};
            float bb[8] = {b0.x,b0.y,b0.z,b0.w,b1.x,b1.y,b1.z,b1.w};
            #pragma unroll
            for (int i=0;i<8;i++)
                #pragma unroll
                for (int j=0;j<8;j++) acc[i][j] += aa[i]*bb[j];
        }
        __syncthreads();
    }
    #pragma unroll
    for (int i=0;i<8;i++){
        float4 c0 = {acc[i][0],acc[i][1],acc[i][2],acc[i][3]};
        float4 c1 = {acc[i][4],acc[i][5],acc[i][6],acc[i][7]};
        *(float4*)(C + (size_t)(m0+ty*8+i)*ldc + n0 + tx*8    ) = c0;
        *(float4*)(C + (size_t)(m0+ty*8+i)*ldc + n0 + tx*8 + 4) = c1;
    }
}

// ------- layer-1 chunk: softmax-weighted aggregation + bias + ELU ------------
// one block per dst node, CF/8 threads, 8 feats/thread, head = t>>3.
// weights computed once per (edge, chunk-head) into LDS tile; dinv precomputed.
__global__ __launch_bounds__(256) void k_agg1(const float* __restrict__ h1c,
        const float* __restrict__ as1, const float* __restrict__ ad1,
        const float* __restrict__ dinv,
        const int* __restrict__ row_start, const int* __restrict__ csr_src,
        const float* __restrict__ b1w, float* __restrict__ x1c,
        int CF, int h0, int chs){
    int n = blockIdx.x, t = threadIdx.x;
    int CHc = 1 << chs;
    __shared__ float ad_s[NH1], dv_s[NH1];
    __shared__ float wt[ET][NH1];
    __shared__ int   st[ET];
    int e0 = row_start[n], e1 = row_start[n+1];
    if (t < CHc){
        ad_s[t] = ad1[n*NH1 + h0 + t];
        dv_s[t] = dinv[n*NH1 + h0 + t];
    }
    __syncthreads();
    int hl = t >> 3;   // chunk-local head of this thread's 8 features
    float acc[8] = {};
    for (int eb = e0; eb < e1; eb += ET){
        int ne = min(ET, e1 - eb);
        for (int idx = t; idx < ne*CHc; idx += blockDim.x){
            int el = idx >> chs, hh = idx & (CHc-1);
            int s = csr_src[eb + el];
            if (hh == 0) st[el] = s;
            wt[el][hh] = expf(lrelu(as1[s*NH1 + h0 + hh] + ad_s[hh])) * dv_s[hh];
        }
        __syncthreads();
        for (int e = 0; e < ne; e++){
            int s = st[e];
            float w = wt[e][hl];
            float4 v0 = *(const float4*)(h1c + (size_t)s*CF + t*8);
            float4 v1 = *(const float4*)(h1c + (size_t)s*CF + t*8 + 4);
            acc[0] += w*v0.x; acc[1] += w*v0.y; acc[2] += w*v0.z; acc[3] += w*v0.w;
            acc[4] += w*v1.x; acc[5] += w*v1.y; acc[6] += w*v1.z; acc[7] += w*v1.w;
        }
        __syncthreads();
    }
    float4 b0 = *(const float4*)(b1w + t*8);
    float4 b1 = *(const float4*)(b1w + t*8 + 4);
    float v[8] = {acc[0]+b0.x, acc[1]+b0.y, acc[2]+b0.z, acc[3]+b0.w,
                  acc[4]+b1.x, acc[5]+b1.y, acc[6]+b1.z, acc[7]+b1.w};
    float o[8];
    #pragma unroll
    for (int i=0;i<8;i++) o[i] = v[i] > 0.f ? v[i] : expm1f(v[i]);
    *(float4*)(x1c + (size_t)n*CF + t*8    ) = float4{o[0],o[1],o[2],o[3]};
    *(float4*)(x1c + (size_t)n*CF + t*8 + 4) = float4{o[4],o[5],o[6],o[7]};
}

// ---------------- zero partials ----------------
__global__ void k_zero(float4* p){
    p[blockIdx.x*256 + threadIdx.x] = float4{0.f,0.f,0.f,0.f};
}

// ------- GEMM2 chunk: partial[ks] += x1c @ Wslice^T over k-range -------------
// m-tile 64, thread tile 4x10; grid (128, KS2); RMW into own partial (no atomics,
// accumulates across chunk dispatches). B pre-offset by chunk col, stride F1.
// LDS pads: APAD=68 (b128-aligned reads, broadcast across lanes),
//           BPAD=162 (even -> b64-aligned; stride-10 cols hit all 32 banks once).
__global__ __launch_bounds__(256) void k_gemm2(const float* __restrict__ A,
                                               const float* __restrict__ B,
                                               float* __restrict__ P, int CF){
    __shared__ float AT[32][68];
    __shared__ float BT[32][162];
    int tid = threadIdx.x;
    int tx = tid & 15;        // 10 cols each
    int ty = tid >> 4;        // 4 rows each
    int m0 = blockIdx.x * 64;
    int kb = blockIdx.y * (CF/KS2);
    int ke = kb + CF/KS2;
    float acc[4][10] = {};
    int ar = tid >> 2;            // 0..63: A stage row
    int aq = (tid & 3) * 8;       // A stage k-offset
    for (int k0 = kb; k0 < ke; k0 += 32){
        #pragma unroll
        for (int hh=0; hh<2; hh++){
            float4 va = *(const float4*)(A + (size_t)(m0+ar)*CF + k0 + aq + 4*hh);
            AT[aq+4*hh+0][ar]=va.x; AT[aq+4*hh+1][ar]=va.y;
            AT[aq+4*hh+2][ar]=va.z; AT[aq+4*hh+3][ar]=va.w;
        }
        for (int i = tid; i < F2*32; i += 256){
            int nn = i >> 5, kk = i & 31;
            BT[kk][nn] = B[(size_t)nn*F1 + k0 + kk];
        }
        __syncthreads();
        #pragma unroll 8
        for (int k=0;k<32;k++){
            float4 av = *(const float4*)&AT[k][ty*4];
            float aa[4] = {av.x, av.y, av.z, av.w};
            float bb[10];
            #pragma unroll
            for (int j=0;j<5;j++){
                float2 bv = *(const float2*)&BT[k][tx*10 + 2*j];
                bb[2*j] = bv.x; bb[2*j+1] = bv.y;
            }
            #pragma unroll
            for (int i=0;i<4;i++)
                #pragma unroll
                for (int j=0;j<10;j++) acc[i][j] += aa[i]*bb[j];
        }
        __syncthreads();
    }
    float* out = P + (size_t)blockIdx.y * N_NODES * F2;
    #pragma unroll
    for (int i=0;i<4;i++){
        float* row = out + (size_t)(m0 + ty*4 + i)*F2 + tx*10;
        #pragma unroll
        for (int j=0;j<5;j++){
            float2 o = *(float2*)(row + 2*j);
            o.x += acc[i][2*j]; o.y += acc[i][2*j+1];
            *(float2*)(row + 2*j) = o;
        }
    }
}

// ---------------- reduce KS2 partials -> h2 ----------------
__global__ __launch_bounds__(256) void k_reduce(const float* __restrict__ P,
                                                float* __restrict__ h2){
    const int NV = N_NODES*F2/4;   // float4 count
    int i = blockIdx.x*256 + threadIdx.x;
    float4 a = ((const float4*)P)[i];
    #pragma unroll
    for (int kb = 1; kb < KS2; kb++){
        float4 b = ((const float4*)P)[(size_t)kb*NV + i];
        a.x += b.x; a.y += b.y; a.z += b.z; a.w += b.w;
    }
    ((float4*)h2)[i] = a;
}

// ---------------- attention dots, layer 2 ----------------
__global__ __launch_bounds__(64) void k_alpha2(const float* __restrict__ h2,
        const float* __restrict__ att_s, const float* __restrict__ att_d,
        float* __restrict__ as2, float* __restrict__ ad2){
    int n = blockIdx.x, t = threadIdx.x;
    float ps = 0.f, pd = 0.f;
    if (t < 40){
        float4 h = *(const float4*)(h2 + (size_t)n*F2 + t*4);
        float4 a = ((const float4*)att_s)[t];
        float4 d = ((const float4*)att_d)[t];
        ps = h.x*a.x + h.y*a.y + h.z*a.z + h.w*a.w;
        pd = h.x*d.x + h.y*d.y + h.z*d.z + h.w*d.w;
    }
    ps += __shfl_xor(ps,1); ps += __shfl_xor(ps,2); ps += __shfl_xor(ps,4);
    pd += __shfl_xor(pd,1); pd += __shfl_xor(pd,2); pd += __shfl_xor(pd,4);
    if (t < 40 && (t & 7) == 0){
        as2[n*NH2 + (t>>3)] = ps;
        ad2[n*NH2 + (t>>3)] = pd;
    }
}

// ------- layer-2 softmax + aggregation + head-mean + b2 ----------------------
__global__ __launch_bounds__(256) void k_agg2(const float* __restrict__ h2,
        const float* __restrict__ as2, const float* __restrict__ ad2,
        const int* __restrict__ row_start, const int* __restrict__ csr_src,
        const float* __restrict__ b2, float* __restrict__ x2){
    int n = blockIdx.x, t = threadIdx.x;
    __shared__ float ad_s[NH2], den_s[NH2], sacc[F2];
    int e0 = row_start[n], e1 = row_start[n+1];
    if (t < NH2) ad_s[t] = ad2[n*NH2 + t];
    __syncthreads();
    if (t < NH2){
        float d = 0.f;
        for (int e=e0;e<e1;e++){
            int s = csr_src[e];
            d += expf(lrelu(as2[s*NH2 + t] + ad_s[t]));
        }
        den_s[t] = d;
    }
    __syncthreads();
    if (t < F2){
        int h = t >> 5;
        float adh  = ad_s[h];
        float dinv = 1.f/den_s[h];
        float acc = 0.f;
        for (int e=e0;e<e1;e++){
            int s = csr_src[e];
            float w = expf(lrelu(as2[s*NH2 + h] + adh)) * dinv;
            acc += w * h2[(size_t)s*F2 + t];
        }
        sacc[t] = acc;
    }
    __syncthreads();
    if (t < OUT_F){
        float v = (sacc[t] + sacc[t+32] + sacc[t+64] + sacc[t+96] + sacc[t+128]) * 0.2f + b2[t];
        x2[n*OUT_F + t] = v;
    }
}

// ---------------- bond scores + softmax over 64 bonds ----------------
__global__ __launch_bounds__(64) void k_bond(const float* __restrict__ x2,
        const int* __restrict__ lefts, const int* __restrict__ rights,
        float* __restrict__ out){
    int b = threadIdx.x;
    int L = lefts[b], R = rights[b];
    float s = 0.f;
    #pragma unroll
    for (int c=0;c<OUT_F;c+=4){
        float4 l4 = *(const float4*)(x2 + (size_t)L*OUT_F + c);
        float4 r4 = *(const float4*)(x2 + (size_t)R*OUT_F + c);
        s += l4.x+l4.y+l4.z+l4.w + r4.x+r4.y+r4.z+r4.w;
    }
    float m = s;
    #pragma unroll
    for (int off=1; off<64; off<<=1) m = fmaxf(m, __shfl_xor(m, off));
    float e = expf(s - m);
    float sum = e;
    #pragma unroll
    for (int off=1; off<64; off<<=1) sum += __shfl_xor(sum, off);
    out[b] = e / sum;
}

extern "C" void kernel_launch(void* const* d_in, const int* in_sizes, int n_in,
                              void* d_out, int out_size, void* d_ws, size_t ws_size,
                              hipStream_t stream){
    const float* x      = (const float*)d_in[0];
    const int*   ei     = (const int*)  d_in[1];
    const int*   lefts  = (const int*)  d_in[2];
    const int*   rights = (const int*)  d_in[3];
    const float* W1     = (const float*)d_in[4];
    const float* att_s1 = (const float*)d_in[5];
    const float* att_d1 = (const float*)d_in[6];
    const float* b1     = (const float*)d_in[7];
    const float* W2     = (const float*)d_in[8];
    const float* att_s2 = (const float*)d_in[9];
    const float* att_d2 = (const float*)d_in[10];
    const float* b2     = (const float*)d_in[11];
    float* out = (float*)d_out;

    // ---- choose chunk width from ws_size (same every call) ----
    // fixed: h2 + partials + as1/ad1/dinv + as2/ad2 + x2 + vsT/vdT + CSR + slack
    size_t fixed = (size_t)(N_NODES*F2 + KS2*N_NODES*F2 + 3*N_NODES*NH1
                          + 2*N_NODES*NH2 + N_NODES*OUT_F + 2*IN_F*NH1
                          + 3*N_NODES + 1 + E_TOT) * 4 + 16384;
    int CF = 512;
    const int cands[2] = {2048, 1024};
    for (int c = 0; c < 2; c++){
        size_t need = fixed + (size_t)N_NODES * cands[c] * 4 * 2;  // h1c + x1c
        if (need <= ws_size){ CF = cands[c]; break; }
    }
    const int NCHUNK = F1 / CF;
    int chs = 0; while ((1 << chs) < CF/HID) chs++;   // log2(heads per chunk)

    char* ws = (char*)d_ws;
    size_t off = 0;
    auto alloc = [&](size_t bytes) -> void* {
        void* p = ws + off;
        off += (bytes + 255) & ~(size_t)255;
        return p;
    };
    float* h1c    = (float*)alloc((size_t)N_NODES*CF*4);
    float* x1c    = (float*)alloc((size_t)N_NODES*CF*4);
    float* part   = (float*)alloc((size_t)KS2*N_NODES*F2*4);   // 21 MB
    float* h2     = (float*)alloc((size_t)N_NODES*F2*4);
    float* as1    = (float*)alloc((size_t)N_NODES*NH1*4);
    float* ad1    = (float*)alloc((size_t)N_NODES*NH1*4);
    float* dinv   = (float*)alloc((size_t)N_NODES*NH1*4);
    float* as2    = (float*)alloc((size_t)N_NODES*NH2*4);
    float* ad2    = (float*)alloc((size_t)N_NODES*NH2*4);
    float* x2     = (float*)alloc((size_t)N_NODES*OUT_F*4);
    float* vsT    = (float*)alloc((size_t)IN_F*NH1*4);
    float* vdT    = (float*)alloc((size_t)IN_F*NH1*4);
    int* counts    = (int*)alloc((size_t)N_NODES*4);
    int* row_start = (int*)alloc((size_t)(N_NODES+1)*4);
    int* cursor    = (int*)alloc((size_t)N_NODES*4);
    int* csr_src   = (int*)alloc((size_t)E_TOT*4);

    // CSR by destination
    k_init_counts<<<32, 256, 0, stream>>>(counts);
    k_count<<<192, 256, 0, stream>>>(ei, counts);
    k_scan<<<1, 1024, 0, stream>>>(counts, row_start, cursor);
    k_fill<<<224, 256, 0, stream>>>(ei, cursor, csr_src);

    // alpha dots + denominators (once, from x — no h1 re-read)
    k_attvec<<<NH1, 128, 0, stream>>>(W1, att_s1, att_d1, vsT, vdT);
    k_alpha1x<<<N_NODES, 128, 0, stream>>>(x, vsT, vdT, as1, ad1);
    k_dinv<<<N_NODES, 64, 0, stream>>>(as1, ad1, row_start, csr_src, dinv);

    // zero gemm2 partial accumulators
    k_zero<<<KS2*N_NODES*F2/4/256, 256, 0, stream>>>((float4*)part);

    for (int c = 0; c < NCHUNK; c++){
        int cb = c * CF;          // feature/column base
        int h0 = cb / HID;        // first head of chunk
        k_gemm1<<<dim3(CF/128, 64), dim3(16,16), 0, stream>>>(
            x, W1 + (size_t)cb*IN_F, h1c, CF);
        k_agg1<<<N_NODES, CF/8, 0, stream>>>(
            h1c, as1, ad1, dinv, row_start, csr_src, b1 + cb, x1c, CF, h0, chs);
        k_gemm2<<<dim3(128, KS2), 256, 0, stream>>>(x1c, W2 + cb, part, CF);
    }

    k_reduce<<<N_NODES*F2/4/256, 256, 0, stream>>>(part, h2);
    k_alpha2<<<N_NODES, 64, 0, stream>>>(h2, att_s2, att_d2, as2, ad2);
    k_agg2<<<N_NODES, 256, 0, stream>>>(h2, as2, ad2, row_start, csr_src, b2, x2);

    k_bond<<<1, 64, 0, stream>>>(x2, lefts, rights, out);
}

// Round 6
// 600.226 us; speedup vs baseline: 3.3042x; 1.1249x over previous
//
#include <hip/hip_runtime.h>
#include <hip/hip_bf16.h>
#include <math.h>

#define N_NODES  8192
#define N_EDGES  49152
#define E_TOT    57344   // edges + self-loops
#define IN_F     128
#define HID      64
#define NH1      64
#define NH2      5
#define OUT_F    32
#define F1       4096    // NH1*HID
#define F2       160     // NH2*OUT_F
#define N_BONDS  64
#define ET       16      // agg1 edge-tile
#define KS2      4       // gemm2 k-split (partial buffers)

__device__ __forceinline__ float lrelu(float x){ return x > 0.f ? x : 0.2f*x; }

// ---------------- CSR build (sort edges by dst) ----------------
__global__ void k_init_counts(int* counts){
    int i = blockIdx.x*256 + threadIdx.x;
    if (i < N_NODES) counts[i] = 1;   // self-loop
}
__global__ void k_count(const int* __restrict__ ei, int* counts){
    int i = blockIdx.x*256 + threadIdx.x;
    if (i < N_EDGES) atomicAdd(&counts[ei[N_EDGES + i]], 1);
}
__global__ __launch_bounds__(1024) void k_scan(const int* __restrict__ counts,
                                               int* __restrict__ row_start,
                                               int* __restrict__ cursor){
    __shared__ int sd[1024];
    int t = threadIdx.x;
    int v[8]; int sum = 0;
    #pragma unroll
    for (int i=0;i<8;i++){ v[i] = counts[t*8+i]; sum += v[i]; }
    sd[t] = sum; __syncthreads();
    for (int off=1; off<1024; off<<=1){
        int vv = (t >= off) ? sd[t-off] : 0;
        __syncthreads();
        sd[t] += vv;
        __syncthreads();
    }
    int run = sd[t] - sum;  // exclusive prefix
    #pragma unroll
    for (int i=0;i<8;i++){ row_start[t*8+i] = run; cursor[t*8+i] = run; run += v[i]; }
    if (t == 1023) row_start[N_NODES] = run;
}
__global__ void k_fill(const int* __restrict__ ei, int* cursor, int* __restrict__ csr_src){
    int i = blockIdx.x*256 + threadIdx.x;
    if (i >= E_TOT) return;
    int s, d;
    if (i < N_EDGES){ s = ei[i]; d = ei[N_EDGES + i]; }
    else { s = i - N_EDGES; d = s; }
    int pos = atomicAdd(&cursor[d], 1);
    csr_src[pos] = s;
}

// ------- attention vectors: vsT[k][h] = sum_c a_s[h,c] * W1[h*64+c, k] -------
__global__ __launch_bounds__(128) void k_attvec(const float* __restrict__ W1,
        const float* __restrict__ a_s, const float* __restrict__ a_d,
        float* __restrict__ vsT, float* __restrict__ vdT){
    int h = blockIdx.x, k = threadIdx.x;
    float s = 0.f, d = 0.f;
    for (int c = 0; c < HID; c++){
        float w = W1[(size_t)(h*HID + c)*IN_F + k];   // 128 lanes: coalesced
        s += a_s[h*HID + c] * w;
        d += a_d[h*HID + c] * w;
    }
    vsT[k*NH1 + h] = s;
    vdT[k*NH1 + h] = d;
}

// ---------- alpha dots from x: as1[n,h] = x[n,:] . vsT[:,h] ------------------
__global__ __launch_bounds__(128) void k_alpha1x(const float* __restrict__ x,
        const float* __restrict__ vsT, const float* __restrict__ vdT,
        float* __restrict__ as1, float* __restrict__ ad1){
    int n = blockIdx.x, t = threadIdx.x;
    __shared__ float xs[IN_F];
    xs[t] = x[(size_t)n*IN_F + t];
    __syncthreads();
    if (t < NH1){
        float s = 0.f, d = 0.f;
        for (int k = 0; k < IN_F; k++){
            float xv = xs[k];
            s += xv * vsT[k*NH1 + t];   // 64 lanes consecutive: coalesced, L1-hot
            d += xv * vdT[k*NH1 + t];
        }
        as1[n*NH1 + t] = s;
        ad1[n*NH1 + t] = d;
    }
}

// ---------- per-node per-head softmax denominators (once, all 64 heads) ------
__global__ __launch_bounds__(64) void k_dinv(const float* __restrict__ as1,
        const float* __restrict__ ad1, const int* __restrict__ row_start,
        const int* __restrict__ csr_src, float* __restrict__ dinv){
    int n = blockIdx.x, h = threadIdx.x;
    float ad = ad1[n*NH1 + h];
    int e0 = row_start[n], e1 = row_start[n+1];
    float d = 0.f;
    for (int e = e0; e < e1; e++){
        int s = csr_src[e];
        d += expf(lrelu(as1[s*NH1 + h] + ad));   // 64 lanes: coalesced 256B row
    }
    dinv[n*NH1 + h] = 1.f / d;
}

// ------- GEMM1 chunk: h1c = x @ Wslice^T  [8192 x CF], K=128 -----------------
// block tile 128x128, thread tile 8x8, transposed LDS tiles (k-major),
// register-prefetch double buffering (next stage's loads issued during compute).
__global__ __launch_bounds__(256) void k_gemm1(const float* __restrict__ A,
                                               const float* __restrict__ B,
                                               float* __restrict__ C, int ldc){
    __shared__ float AT[32][132];
    __shared__ float BT[32][132];
    int tx = threadIdx.x, ty = threadIdx.y;
    int tid = ty*16 + tx;
    int m0 = blockIdx.y * 128;
    int n0 = blockIdx.x * 128;
    float acc[8][8] = {};
    int r  = tid >> 1;          // 0..127
    int kq = (tid & 1) * 16;    // 0 or 16
    const float* Ab = A + (size_t)(m0 + r)*IN_F + kq;
    const float* Bb = B + (size_t)(n0 + r)*IN_F + kq;
    float4 pa[4], pb[4];
    #pragma unroll
    for (int q=0;q<4;q++){ pa[q] = *(const float4*)(Ab + 4*q); pb[q] = *(const float4*)(Bb + 4*q); }
    for (int k0 = 0; k0 < IN_F; k0 += 32){
        #pragma unroll
        for (int q=0;q<4;q++){
            int kk = kq + 4*q;
            AT[kk+0][r]=pa[q].x; AT[kk+1][r]=pa[q].y; AT[kk+2][r]=pa[q].z; AT[kk+3][r]=pa[q].w;
            BT[kk+0][r]=pb[q].x; BT[kk+1][r]=pb[q].y; BT[kk+2][r]=pb[q].z; BT[kk+3][r]=pb[q].w;
        }
        __syncthreads();
        if (k0 + 32 < IN_F){
            #pragma unroll
            for (int q=0;q<4;q++){
                pa[q] = *(const float4*)(Ab + k0 + 32 + 4*q);
                pb[q] = *(const float4*)(Bb + k0 + 32 + 4*q);
            }
        }
        #pragma unroll 4
        for (int k=0;k<32;k++){
            float4 a0 = *(const float4*)&AT[k][ty*8];
            float4 a1 = *(const float4*)&AT[k][ty*8+4];
            float4 b0 = *(const float4*)&BT[k][tx*8];
            float4 b1 = *(const float4*)&BT[k][tx*8+4];
            float aa[8] = {a0.x,a0.y,a0.z,a0.w,a1.x,a1.y,a1.z,a1.w};
            float bb[8] = {b0.x,b0.y,b0.z,b0.w,b1.x,b1.y,b1.z,b1.w};
            #pragma unroll
            for (int i=0;i<8;i++)
                #pragma unroll
                for (int j=0;j<8;j++) acc[i][j] += aa[i]*bb[j];
        }
        __syncthreads();
    }
    #pragma unroll
    for (int i=0;i<8;i++){
        float4 c0 = {acc[i][0],acc[i][1],acc[i][2],acc[i][3]};
        float4 c1 = {acc[i][4],acc[i][5],acc[i][6],acc[i][7]};
        *(float4*)(C + (size_t)(m0+ty*8+i)*ldc + n0 + tx*8    ) = c0;
        *(float4*)(C + (size_t)(m0+ty*8+i)*ldc + n0 + tx*8 + 4) = c1;
    }
}

// ------- layer-1 chunk: softmax-weighted aggregation + bias + ELU ------------
// one block per dst node, CF/8 threads, 8 feats/thread, head = t>>3.
// weights computed once per (edge, chunk-head) into LDS tile; dinv precomputed.
__global__ __launch_bounds__(256) void k_agg1(const float* __restrict__ h1c,
        const float* __restrict__ as1, const float* __restrict__ ad1,
        const float* __restrict__ dinv,
        const int* __restrict__ row_start, const int* __restrict__ csr_src,
        const float* __restrict__ b1w, float* __restrict__ x1c,
        int CF, int h0, int chs){
    int n = blockIdx.x, t = threadIdx.x;
    int CHc = 1 << chs;
    __shared__ float ad_s[NH1], dv_s[NH1];
    __shared__ float wt[ET][NH1];
    __shared__ int   st[ET];
    int e0 = row_start[n], e1 = row_start[n+1];
    if (t < CHc){
        ad_s[t] = ad1[n*NH1 + h0 + t];
        dv_s[t] = dinv[n*NH1 + h0 + t];
    }
    __syncthreads();
    int hl = t >> 3;   // chunk-local head of this thread's 8 features
    float acc[8] = {};
    for (int eb = e0; eb < e1; eb += ET){
        int ne = min(ET, e1 - eb);
        for (int idx = t; idx < ne*CHc; idx += blockDim.x){
            int el = idx >> chs, hh = idx & (CHc-1);
            int s = csr_src[eb + el];
            if (hh == 0) st[el] = s;
            wt[el][hh] = expf(lrelu(as1[s*NH1 + h0 + hh] + ad_s[hh])) * dv_s[hh];
        }
        __syncthreads();
        for (int e = 0; e < ne; e++){
            int s = st[e];
            float w = wt[e][hl];
            float4 v0 = *(const float4*)(h1c + (size_t)s*CF + t*8);
            float4 v1 = *(const float4*)(h1c + (size_t)s*CF + t*8 + 4);
            acc[0] += w*v0.x; acc[1] += w*v0.y; acc[2] += w*v0.z; acc[3] += w*v0.w;
            acc[4] += w*v1.x; acc[5] += w*v1.y; acc[6] += w*v1.z; acc[7] += w*v1.w;
        }
        __syncthreads();
    }
    float4 b0 = *(const float4*)(b1w + t*8);
    float4 b1 = *(const float4*)(b1w + t*8 + 4);
    float v[8] = {acc[0]+b0.x, acc[1]+b0.y, acc[2]+b0.z, acc[3]+b0.w,
                  acc[4]+b1.x, acc[5]+b1.y, acc[6]+b1.z, acc[7]+b1.w};
    float o[8];
    #pragma unroll
    for (int i=0;i<8;i++) o[i] = v[i] > 0.f ? v[i] : expm1f(v[i]);
    *(float4*)(x1c + (size_t)n*CF + t*8    ) = float4{o[0],o[1],o[2],o[3]};
    *(float4*)(x1c + (size_t)n*CF + t*8 + 4) = float4{o[4],o[5],o[6],o[7]};
}

// ---------------- zero partials ----------------
__global__ void k_zero(float4* p){
    p[blockIdx.x*256 + threadIdx.x] = float4{0.f,0.f,0.f,0.f};
}

// ------- GEMM2 chunk: partial[ks] += x1c @ Wslice^T over k-range -------------
// m-tile 64, thread tile 4x10; grid (128, KS2); RMW into own partial.
// Register-prefetch double buffering on both LDS stages.
// LDS pads: APAD=68, BPAD=162 (conflict-free, see R5 notes).
__global__ __launch_bounds__(256) void k_gemm2(const float* __restrict__ A,
                                               const float* __restrict__ B,
                                               float* __restrict__ P, int CF){
    __shared__ float AT[32][68];
    __shared__ float BT[32][162];
    int tid = threadIdx.x;
    int tx = tid & 15;        // 10 cols each
    int ty = tid >> 4;        // 4 rows each
    int m0 = blockIdx.x * 64;
    int kb = blockIdx.y * (CF/KS2);
    int ke = kb + CF/KS2;
    float acc[4][10] = {};
    int ar = tid >> 2;            // 0..63: A stage row
    int aq = (tid & 3) * 8;       // A stage k-offset
    const float* Ab = A + (size_t)(m0+ar)*CF + aq;
    // B staging: 5 float4-tasks per thread; task j -> row nn=j>>3, k-off (j&7)*4
    int bn[5], bk[5];
    #pragma unroll
    for (int p=0;p<5;p++){ int j = tid + 256*p; bn[p] = j >> 3; bk[p] = (j & 7)*4; }
    float4 pa[2], pb[5];
    #pragma unroll
    for (int hh=0;hh<2;hh++) pa[hh] = *(const float4*)(Ab + kb + 4*hh);
    #pragma unroll
    for (int p=0;p<5;p++) pb[p] = *(const float4*)(B + (size_t)bn[p]*F1 + kb + bk[p]);
    for (int k0 = kb; k0 < ke; k0 += 32){
        #pragma unroll
        for (int hh=0;hh<2;hh++){
            AT[aq+4*hh+0][ar]=pa[hh].x; AT[aq+4*hh+1][ar]=pa[hh].y;
            AT[aq+4*hh+2][ar]=pa[hh].z; AT[aq+4*hh+3][ar]=pa[hh].w;
        }
        #pragma unroll
        for (int p=0;p<5;p++){
            BT[bk[p]+0][bn[p]]=pb[p].x; BT[bk[p]+1][bn[p]]=pb[p].y;
            BT[bk[p]+2][bn[p]]=pb[p].z; BT[bk[p]+3][bn[p]]=pb[p].w;
        }
        __syncthreads();
        if (k0 + 32 < ke){
            #pragma unroll
            for (int hh=0;hh<2;hh++) pa[hh] = *(const float4*)(Ab + k0 + 32 + 4*hh);
            #pragma unroll
            for (int p=0;p<5;p++) pb[p] = *(const float4*)(B + (size_t)bn[p]*F1 + k0 + 32 + bk[p]);
        }
        #pragma unroll 8
        for (int k=0;k<32;k++){
            float4 av = *(const float4*)&AT[k][ty*4];
            float aa[4] = {av.x, av.y, av.z, av.w};
            float bb[10];
            #pragma unroll
            for (int j=0;j<5;j++){
                float2 bv = *(const float2*)&BT[k][tx*10 + 2*j];
                bb[2*j] = bv.x; bb[2*j+1] = bv.y;
            }
            #pragma unroll
            for (int i=0;i<4;i++)
                #pragma unroll
                for (int j=0;j<10;j++) acc[i][j] += aa[i]*bb[j];
        }
        __syncthreads();
    }
    float* out = P + (size_t)blockIdx.y * N_NODES * F2;
    #pragma unroll
    for (int i=0;i<4;i++){
        float* row = out + (size_t)(m0 + ty*4 + i)*F2 + tx*10;
        #pragma unroll
        for (int j=0;j<5;j++){
            float2 o = *(float2*)(row + 2*j);
            o.x += acc[i][2*j]; o.y += acc[i][2*j+1];
            *(float2*)(row + 2*j) = o;
        }
    }
}

// ---------------- reduce KS2 partials -> h2 ----------------
__global__ __launch_bounds__(256) void k_reduce(const float* __restrict__ P,
                                                float* __restrict__ h2){
    const int NV = N_NODES*F2/4;   // float4 count
    int i = blockIdx.x*256 + threadIdx.x;
    float4 a = ((const float4*)P)[i];
    #pragma unroll
    for (int kb = 1; kb < KS2; kb++){
        float4 b = ((const float4*)P)[(size_t)kb*NV + i];
        a.x += b.x; a.y += b.y; a.z += b.z; a.w += b.w;
    }
    ((float4*)h2)[i] = a;
}

// ---------------- attention dots, layer 2 ----------------
__global__ __launch_bounds__(64) void k_alpha2(const float* __restrict__ h2,
        const float* __restrict__ att_s, const float* __restrict__ att_d,
        float* __restrict__ as2, float* __restrict__ ad2){
    int n = blockIdx.x, t = threadIdx.x;
    float ps = 0.f, pd = 0.f;
    if (t < 40){
        float4 h = *(const float4*)(h2 + (size_t)n*F2 + t*4);
        float4 a = ((const float4*)att_s)[t];
        float4 d = ((const float4*)att_d)[t];
        ps = h.x*a.x + h.y*a.y + h.z*a.z + h.w*a.w;
        pd = h.x*d.x + h.y*d.y + h.z*d.z + h.w*d.w;
    }
    ps += __shfl_xor(ps,1); ps += __shfl_xor(ps,2); ps += __shfl_xor(ps,4);
    pd += __shfl_xor(pd,1); pd += __shfl_xor(pd,2); pd += __shfl_xor(pd,4);
    if (t < 40 && (t & 7) == 0){
        as2[n*NH2 + (t>>3)] = ps;
        ad2[n*NH2 + (t>>3)] = pd;
    }
}

// ------- layer-2 softmax + aggregation + head-mean + b2 ----------------------
__global__ __launch_bounds__(256) void k_agg2(const float* __restrict__ h2,
        const float* __restrict__ as2, const float* __restrict__ ad2,
        const int* __restrict__ row_start, const int* __restrict__ csr_src,
        const float* __restrict__ b2, float* __restrict__ x2){
    int n = blockIdx.x, t = threadIdx.x;
    __shared__ float ad_s[NH2], den_s[NH2], sacc[F2];
    int e0 = row_start[n], e1 = row_start[n+1];
    if (t < NH2) ad_s[t] = ad2[n*NH2 + t];
    __syncthreads();
    if (t < NH2){
        float d = 0.f;
        for (int e=e0;e<e1;e++){
            int s = csr_src[e];
            d += expf(lrelu(as2[s*NH2 + t] + ad_s[t]));
        }
        den_s[t] = d;
    }
    __syncthreads();
    if (t < F2){
        int h = t >> 5;
        float adh  = ad_s[h];
        float dinv = 1.f/den_s[h];
        float acc = 0.f;
        for (int e=e0;e<e1;e++){
            int s = csr_src[e];
            float w = expf(lrelu(as2[s*NH2 + h] + adh)) * dinv;
            acc += w * h2[(size_t)s*F2 + t];
        }
        sacc[t] = acc;
    }
    __syncthreads();
    if (t < OUT_F){
        float v = (sacc[t] + sacc[t+32] + sacc[t+64] + sacc[t+96] + sacc[t+128]) * 0.2f + b2[t];
        x2[n*OUT_F + t] = v;
    }
}

// ---------------- bond scores + softmax over 64 bonds ----------------
__global__ __launch_bounds__(64) void k_bond(const float* __restrict__ x2,
        const int* __restrict__ lefts, const int* __restrict__ rights,
        float* __restrict__ out){
    int b = threadIdx.x;
    int L = lefts[b], R = rights[b];
    float s = 0.f;
    #pragma unroll
    for (int c=0;c<OUT_F;c+=4){
        float4 l4 = *(const float4*)(x2 + (size_t)L*OUT_F + c);
        float4 r4 = *(const float4*)(x2 + (size_t)R*OUT_F + c);
        s += l4.x+l4.y+l4.z+l4.w + r4.x+r4.y+r4.z+r4.w;
    }
    float m = s;
    #pragma unroll
    for (int off=1; off<64; off<<=1) m = fmaxf(m, __shfl_xor(m, off));
    float e = expf(s - m);
    float sum = e;
    #pragma unroll
    for (int off=1; off<64; off<<=1) sum += __shfl_xor(sum, off);
    out[b] = e / sum;
}

extern "C" void kernel_launch(void* const* d_in, const int* in_sizes, int n_in,
                              void* d_out, int out_size, void* d_ws, size_t ws_size,
                              hipStream_t stream){
    const float* x      = (const float*)d_in[0];
    const int*   ei     = (const int*)  d_in[1];
    const int*   lefts  = (const int*)  d_in[2];
    const int*   rights = (const int*)  d_in[3];
    const float* W1     = (const float*)d_in[4];
    const float* att_s1 = (const float*)d_in[5];
    const float* att_d1 = (const float*)d_in[6];
    const float* b1     = (const float*)d_in[7];
    const float* W2     = (const float*)d_in[8];
    const float* att_s2 = (const float*)d_in[9];
    const float* att_d2 = (const float*)d_in[10];
    const float* b2     = (const float*)d_in[11];
    float* out = (float*)d_out;

    // ---- choose chunk width from ws_size (same every call) ----
    size_t fixed = (size_t)(N_NODES*F2 + KS2*N_NODES*F2 + 3*N_NODES*NH1
                          + 2*N_NODES*NH2 + N_NODES*OUT_F + 2*IN_F*NH1
                          + 3*N_NODES + 1 + E_TOT) * 4 + 16384;
    int CF = 512;
    const int cands[2] = {2048, 1024};
    for (int c = 0; c < 2; c++){
        size_t need = fixed + (size_t)N_NODES * cands[c] * 4 * 2;  // h1c + x1c
        if (need <= ws_size){ CF = cands[c]; break; }
    }
    const int NCHUNK = F1 / CF;
    int chs = 0; while ((1 << chs) < CF/HID) chs++;   // log2(heads per chunk)

    char* ws = (char*)d_ws;
    size_t off = 0;
    auto alloc = [&](size_t bytes) -> void* {
        void* p = ws + off;
        off += (bytes + 255) & ~(size_t)255;
        return p;
    };
    float* h1c    = (float*)alloc((size_t)N_NODES*CF*4);
    float* x1c    = (float*)alloc((size_t)N_NODES*CF*4);
    float* part   = (float*)alloc((size_t)KS2*N_NODES*F2*4);   // 21 MB
    float* h2     = (float*)alloc((size_t)N_NODES*F2*4);
    float* as1    = (float*)alloc((size_t)N_NODES*NH1*4);
    float* ad1    = (float*)alloc((size_t)N_NODES*NH1*4);
    float* dinv   = (float*)alloc((size_t)N_NODES*NH1*4);
    float* as2    = (float*)alloc((size_t)N_NODES*NH2*4);
    float* ad2    = (float*)alloc((size_t)N_NODES*NH2*4);
    float* x2     = (float*)alloc((size_t)N_NODES*OUT_F*4);
    float* vsT    = (float*)alloc((size_t)IN_F*NH1*4);
    float* vdT    = (float*)alloc((size_t)IN_F*NH1*4);
    int* counts    = (int*)alloc((size_t)N_NODES*4);
    int* row_start = (int*)alloc((size_t)(N_NODES+1)*4);
    int* cursor    = (int*)alloc((size_t)N_NODES*4);
    int* csr_src   = (int*)alloc((size_t)E_TOT*4);

    // CSR by destination
    k_init_counts<<<32, 256, 0, stream>>>(counts);
    k_count<<<192, 256, 0, stream>>>(ei, counts);
    k_scan<<<1, 1024, 0, stream>>>(counts, row_start, cursor);
    k_fill<<<224, 256, 0, stream>>>(ei, cursor, csr_src);

    // alpha dots + denominators (once, from x — no h1 re-read)
    k_attvec<<<NH1, 128, 0, stream>>>(W1, att_s1, att_d1, vsT, vdT);
    k_alpha1x<<<N_NODES, 128, 0, stream>>>(x, vsT, vdT, as1, ad1);
    k_dinv<<<N_NODES, 64, 0, stream>>>(as1, ad1, row_start, csr_src, dinv);

    // zero gemm2 partial accumulators
    k_zero<<<KS2*N_NODES*F2/4/256, 256, 0, stream>>>((float4*)part);

    for (int c = 0; c < NCHUNK; c++){
        int cb = c * CF;          // feature/column base
        int h0 = cb / HID;        // first head of chunk
        k_gemm1<<<dim3(CF/128, 64), dim3(16,16), 0, stream>>>(
            x, W1 + (size_t)cb*IN_F, h1c, CF);
        k_agg1<<<N_NODES, CF/8, 0, stream>>>(
            h1c, as1, ad1, dinv, row_start, csr_src, b1 + cb, x1c, CF, h0, chs);
        k_gemm2<<<dim3(128, KS2), 256, 0, stream>>>(x1c, W2 + cb, part, CF);
    }

    k_reduce<<<N_NODES*F2/4/256, 256, 0, stream>>>(part, h2);
    k_alpha2<<<N_NODES, 64, 0, stream>>>(h2, att_s2, att_d2, as2, ad2);
    k_agg2<<<N_NODES, 256, 0, stream>>>(h2, as2, ad2, row_start, csr_src, b2, x2);

    k_bond<<<1, 64, 0, stream>>>(x2, lefts, rights, out);
}

// Round 7
// 564.805 us; speedup vs baseline: 3.5115x; 1.0627x over previous
//
#include <hip/hip_runtime.h>
#include <hip/hip_bf16.h>
#include <math.h>

#define N_NODES  8192
#define N_EDGES  49152
#define E_TOT    57344   // edges + self-loops
#define IN_F     128
#define HID      64
#define NH1      64
#define NH2      5
#define OUT_F    32
#define F1       4096    // NH1*HID
#define F2       160     // NH2*OUT_F
#define N_BONDS  64
#define ET       16      // agg1 edge-tile
#define KS2      2       // gemm2 k-split (partial buffers)

typedef short bf16x8 __attribute__((ext_vector_type(8)));
typedef float f32x4  __attribute__((ext_vector_type(4)));

__device__ __forceinline__ float lrelu(float x){ return x > 0.f ? x : 0.2f*x; }

__device__ __forceinline__ unsigned short bf16_rne(float f){
    unsigned u = __float_as_uint(f);
    unsigned r = u + 0x7FFF + ((u >> 16) & 1);
    return (unsigned short)(r >> 16);
}
__device__ __forceinline__ float bf16f(unsigned short h){
    return __uint_as_float((unsigned)h << 16);
}

// ---------------- CSR build (sort edges by dst) ----------------
__global__ void k_init_counts(int* counts){
    int i = blockIdx.x*256 + threadIdx.x;
    if (i < N_NODES) counts[i] = 1;   // self-loop
}
__global__ void k_count(const int* __restrict__ ei, int* counts){
    int i = blockIdx.x*256 + threadIdx.x;
    if (i < N_EDGES) atomicAdd(&counts[ei[N_EDGES + i]], 1);
}
__global__ __launch_bounds__(1024) void k_scan(const int* __restrict__ counts,
                                               int* __restrict__ row_start,
                                               int* __restrict__ cursor){
    __shared__ int sd[1024];
    int t = threadIdx.x;
    int v[8]; int sum = 0;
    #pragma unroll
    for (int i=0;i<8;i++){ v[i] = counts[t*8+i]; sum += v[i]; }
    sd[t] = sum; __syncthreads();
    for (int off=1; off<1024; off<<=1){
        int vv = (t >= off) ? sd[t-off] : 0;
        __syncthreads();
        sd[t] += vv;
        __syncthreads();
    }
    int run = sd[t] - sum;  // exclusive prefix
    #pragma unroll
    for (int i=0;i<8;i++){ row_start[t*8+i] = run; cursor[t*8+i] = run; run += v[i]; }
    if (t == 1023) row_start[N_NODES] = run;
}
__global__ void k_fill(const int* __restrict__ ei, int* cursor, int* __restrict__ csr_src){
    int i = blockIdx.x*256 + threadIdx.x;
    if (i >= E_TOT) return;
    int s, d;
    if (i < N_EDGES){ s = ei[i]; d = ei[N_EDGES + i]; }
    else { s = i - N_EDGES; d = s; }
    int pos = atomicAdd(&cursor[d], 1);
    csr_src[pos] = s;
}

// ---------------- split fp32 -> bf16 hi/lo planes ----------------
__global__ void k_split(const float* __restrict__ in, unsigned short* __restrict__ hi,
                        unsigned short* __restrict__ lo, int n){
    int i = blockIdx.x*256 + threadIdx.x;
    if (i < n){
        float f = in[i];
        unsigned short h = bf16_rne(f);
        hi[i] = h;
        lo[i] = bf16_rne(f - bf16f(h));
    }
}

// ------- attention vectors: vsT[k][h] = sum_c a_s[h,c] * W1[h*64+c, k] -------
__global__ __launch_bounds__(128) void k_attvec(const float* __restrict__ W1,
        const float* __restrict__ a_s, const float* __restrict__ a_d,
        float* __restrict__ vsT, float* __restrict__ vdT){
    int h = blockIdx.x, k = threadIdx.x;
    float s = 0.f, d = 0.f;
    for (int c = 0; c < HID; c++){
        float w = W1[(size_t)(h*HID + c)*IN_F + k];   // 128 lanes: coalesced
        s += a_s[h*HID + c] * w;
        d += a_d[h*HID + c] * w;
    }
    vsT[k*NH1 + h] = s;
    vdT[k*NH1 + h] = d;
}

// ---------- alpha dots from x: as1[n,h] = x[n,:] . vsT[:,h] ------------------
__global__ __launch_bounds__(128) void k_alpha1x(const float* __restrict__ x,
        const float* __restrict__ vsT, const float* __restrict__ vdT,
        float* __restrict__ as1, float* __restrict__ ad1){
    int n = blockIdx.x, t = threadIdx.x;
    __shared__ float xs[IN_F];
    xs[t] = x[(size_t)n*IN_F + t];
    __syncthreads();
    if (t < NH1){
        float s = 0.f, d = 0.f;
        for (int k = 0; k < IN_F; k++){
            float xv = xs[k];
            s += xv * vsT[k*NH1 + t];
            d += xv * vdT[k*NH1 + t];
        }
        as1[n*NH1 + t] = s;
        ad1[n*NH1 + t] = d;
    }
}

// ---------- per-node per-head softmax denominators (once, all 64 heads) ------
__global__ __launch_bounds__(64) void k_dinv(const float* __restrict__ as1,
        const float* __restrict__ ad1, const int* __restrict__ row_start,
        const int* __restrict__ csr_src, float* __restrict__ dinv){
    int n = blockIdx.x, h = threadIdx.x;
    float ad = ad1[n*NH1 + h];
    int e0 = row_start[n], e1 = row_start[n+1];
    float d = 0.f;
    for (int e = e0; e < e1; e++){
        int s = csr_src[e];
        d += expf(lrelu(as1[s*NH1 + h] + ad));
    }
    dinv[n*NH1 + h] = 1.f / d;
}

// ------- GEMM1 chunk (MFMA split-bf16): h1c = x @ Wslice^T, K=128 ------------
// grid (CF/128, 64); 4 waves in 2x2, each 64x64 (4x4 tiles of 16x16).
// All operands L2-resident bf16 planes -> direct global fragment loads, no LDS.
__global__ __launch_bounds__(256) void k_gemm1(const unsigned short* __restrict__ xhi,
        const unsigned short* __restrict__ xlo,
        const unsigned short* __restrict__ w1hi,
        const unsigned short* __restrict__ w1lo,
        float* __restrict__ C, int ldc, int cb){
    int wave = threadIdx.x >> 6, lane = threadIdx.x & 63;
    int wm = wave & 1, wn = wave >> 1;
    int m0  = blockIdx.y*128 + wm*64;
    int n0  = blockIdx.x*128 + wn*64;     // chunk-local col
    int q = lane >> 4, l16 = lane & 15;
    f32x4 acc[4][4] = {};
    #pragma unroll
    for (int ks = 0; ks < 4; ks++){
        int kb = ks*32 + q*8;
        bf16x8 ah[4], al[4], bh[4], bl[4];
        #pragma unroll
        for (int mi=0;mi<4;mi++){
            size_t r = (size_t)(m0 + mi*16 + l16)*IN_F + kb;
            ah[mi] = *(const bf16x8*)(xhi + r);
            al[mi] = *(const bf16x8*)(xlo + r);
        }
        #pragma unroll
        for (int ni=0;ni<4;ni++){
            size_t r = (size_t)(cb + n0 + ni*16 + l16)*IN_F + kb;
            bh[ni] = *(const bf16x8*)(w1hi + r);
            bl[ni] = *(const bf16x8*)(w1lo + r);
        }
        #pragma unroll
        for (int mi=0;mi<4;mi++)
            #pragma unroll
            for (int ni=0;ni<4;ni++){
                acc[mi][ni] = __builtin_amdgcn_mfma_f32_16x16x32_bf16(ah[mi], bh[ni], acc[mi][ni], 0,0,0);
                acc[mi][ni] = __builtin_amdgcn_mfma_f32_16x16x32_bf16(ah[mi], bl[ni], acc[mi][ni], 0,0,0);
                acc[mi][ni] = __builtin_amdgcn_mfma_f32_16x16x32_bf16(al[mi], bh[ni], acc[mi][ni], 0,0,0);
            }
    }
    #pragma unroll
    for (int mi=0;mi<4;mi++)
        #pragma unroll
        for (int ni=0;ni<4;ni++)
            #pragma unroll
            for (int i=0;i<4;i++)
                C[(size_t)(m0 + mi*16 + q*4 + i)*ldc + n0 + ni*16 + l16] = acc[mi][ni][i];
}

// ------- layer-1 chunk: softmax-weighted aggregation + bias + ELU ------------
__global__ __launch_bounds__(256) void k_agg1(const float* __restrict__ h1c,
        const float* __restrict__ as1, const float* __restrict__ ad1,
        const float* __restrict__ dinv,
        const int* __restrict__ row_start, const int* __restrict__ csr_src,
        const float* __restrict__ b1w, float* __restrict__ x1c,
        int CF, int h0, int chs){
    int n = blockIdx.x, t = threadIdx.x;
    int CHc = 1 << chs;
    __shared__ float ad_s[NH1], dv_s[NH1];
    __shared__ float wt[ET][NH1];
    __shared__ int   st[ET];
    int e0 = row_start[n], e1 = row_start[n+1];
    if (t < CHc){
        ad_s[t] = ad1[n*NH1 + h0 + t];
        dv_s[t] = dinv[n*NH1 + h0 + t];
    }
    __syncthreads();
    int hl = t >> 3;
    float acc[8] = {};
    for (int eb = e0; eb < e1; eb += ET){
        int ne = min(ET, e1 - eb);
        for (int idx = t; idx < ne*CHc; idx += blockDim.x){
            int el = idx >> chs, hh = idx & (CHc-1);
            int s = csr_src[eb + el];
            if (hh == 0) st[el] = s;
            wt[el][hh] = expf(lrelu(as1[s*NH1 + h0 + hh] + ad_s[hh])) * dv_s[hh];
        }
        __syncthreads();
        for (int e = 0; e < ne; e++){
            int s = st[e];
            float w = wt[e][hl];
            float4 v0 = *(const float4*)(h1c + (size_t)s*CF + t*8);
            float4 v1 = *(const float4*)(h1c + (size_t)s*CF + t*8 + 4);
            acc[0] += w*v0.x; acc[1] += w*v0.y; acc[2] += w*v0.z; acc[3] += w*v0.w;
            acc[4] += w*v1.x; acc[5] += w*v1.y; acc[6] += w*v1.z; acc[7] += w*v1.w;
        }
        __syncthreads();
    }
    float4 b0 = *(const float4*)(b1w + t*8);
    float4 b1 = *(const float4*)(b1w + t*8 + 4);
    float v[8] = {acc[0]+b0.x, acc[1]+b0.y, acc[2]+b0.z, acc[3]+b0.w,
                  acc[4]+b1.x, acc[5]+b1.y, acc[6]+b1.z, acc[7]+b1.w};
    float o[8];
    #pragma unroll
    for (int i=0;i<8;i++) o[i] = v[i] > 0.f ? v[i] : expm1f(v[i]);
    *(float4*)(x1c + (size_t)n*CF + t*8    ) = float4{o[0],o[1],o[2],o[3]};
    *(float4*)(x1c + (size_t)n*CF + t*8 + 4) = float4{o[4],o[5],o[6],o[7]};
}

// ---------------- zero partials ----------------
__global__ void k_zero(float4* p){
    p[blockIdx.x*256 + threadIdx.x] = float4{0.f,0.f,0.f,0.f};
}

// ------- GEMM2 chunk (MFMA split-bf16): partial[ks] += x1c @ Wslice^T --------
// grid (128, KS2); 4 waves, each a 16-row strip x 160 cols (10 n-tiles).
// A (x1c fp32) split hi/lo on the fly; B from pre-split W2 planes (L2-hot).
__global__ __launch_bounds__(256) void k_gemm2(const float* __restrict__ x1c,
        const unsigned short* __restrict__ w2hi,
        const unsigned short* __restrict__ w2lo,
        float* __restrict__ P, int CF, int cb){
    int wave = threadIdx.x >> 6, lane = threadIdx.x & 63;
    int m0 = blockIdx.x*64 + wave*16;
    int q = lane >> 4, l16 = lane & 15;
    int kb0 = blockIdx.y * (CF/KS2);
    int nks = (CF/KS2)/32;
    f32x4 acc[10] = {};
    for (int ks = 0; ks < nks; ks++){
        int kb = kb0 + ks*32 + q*8;
        const float* ap = x1c + (size_t)(m0 + l16)*CF + kb;
        float4 a0 = *(const float4*)ap;
        float4 a1 = *(const float4*)(ap + 4);
        float av[8] = {a0.x,a0.y,a0.z,a0.w,a1.x,a1.y,a1.z,a1.w};
        bf16x8 ah, al;
        #pragma unroll
        for (int j=0;j<8;j++){
            unsigned short h = bf16_rne(av[j]);
            ah[j] = (short)h;
            al[j] = (short)bf16_rne(av[j] - bf16f(h));
        }
        #pragma unroll
        for (int ni=0; ni<10; ni++){
            size_t r = (size_t)(ni*16 + l16)*F1 + cb + kb;
            bf16x8 bh = *(const bf16x8*)(w2hi + r);
            bf16x8 bl = *(const bf16x8*)(w2lo + r);
            acc[ni] = __builtin_amdgcn_mfma_f32_16x16x32_bf16(ah, bh, acc[ni], 0,0,0);
            acc[ni] = __builtin_amdgcn_mfma_f32_16x16x32_bf16(ah, bl, acc[ni], 0,0,0);
            acc[ni] = __builtin_amdgcn_mfma_f32_16x16x32_bf16(al, bh, acc[ni], 0,0,0);
        }
    }
    float* out = P + (size_t)blockIdx.y * N_NODES * F2;
    #pragma unroll
    for (int ni=0;ni<10;ni++)
        #pragma unroll
        for (int i=0;i<4;i++){
            size_t idx = (size_t)(m0 + q*4 + i)*F2 + ni*16 + l16;
            out[idx] += acc[ni][i];   // unique ownership RMW, accumulates chunks
        }
}

// ---------------- reduce KS2 partials -> h2 ----------------
__global__ __launch_bounds__(256) void k_reduce(const float* __restrict__ P,
                                                float* __restrict__ h2){
    const int NV = N_NODES*F2/4;
    int i = blockIdx.x*256 + threadIdx.x;
    float4 a = ((const float4*)P)[i];
    #pragma unroll
    for (int kb = 1; kb < KS2; kb++){
        float4 b = ((const float4*)P)[(size_t)kb*NV + i];
        a.x += b.x; a.y += b.y; a.z += b.z; a.w += b.w;
    }
    ((float4*)h2)[i] = a;
}

// ---------------- attention dots, layer 2 ----------------
__global__ __launch_bounds__(64) void k_alpha2(const float* __restrict__ h2,
        const float* __restrict__ att_s, const float* __restrict__ att_d,
        float* __restrict__ as2, float* __restrict__ ad2){
    int n = blockIdx.x, t = threadIdx.x;
    float ps = 0.f, pd = 0.f;
    if (t < 40){
        float4 h = *(const float4*)(h2 + (size_t)n*F2 + t*4);
        float4 a = ((const float4*)att_s)[t];
        float4 d = ((const float4*)att_d)[t];
        ps = h.x*a.x + h.y*a.y + h.z*a.z + h.w*a.w;
        pd = h.x*d.x + h.y*d.y + h.z*d.z + h.w*d.w;
    }
    ps += __shfl_xor(ps,1); ps += __shfl_xor(ps,2); ps += __shfl_xor(ps,4);
    pd += __shfl_xor(pd,1); pd += __shfl_xor(pd,2); pd += __shfl_xor(pd,4);
    if (t < 40 && (t & 7) == 0){
        as2[n*NH2 + (t>>3)] = ps;
        ad2[n*NH2 + (t>>3)] = pd;
    }
}

// ------- layer-2 softmax + aggregation + head-mean + b2 ----------------------
__global__ __launch_bounds__(256) void k_agg2(const float* __restrict__ h2,
        const float* __restrict__ as2, const float* __restrict__ ad2,
        const int* __restrict__ row_start, const int* __restrict__ csr_src,
        const float* __restrict__ b2, float* __restrict__ x2){
    int n = blockIdx.x, t = threadIdx.x;
    __shared__ float ad_s[NH2], den_s[NH2], sacc[F2];
    int e0 = row_start[n], e1 = row_start[n+1];
    if (t < NH2) ad_s[t] = ad2[n*NH2 + t];
    __syncthreads();
    if (t < NH2){
        float d = 0.f;
        for (int e=e0;e<e1;e++){
            int s = csr_src[e];
            d += expf(lrelu(as2[s*NH2 + t] + ad_s[t]));
        }
        den_s[t] = d;
    }
    __syncthreads();
    if (t < F2){
        int h = t >> 5;
        float adh  = ad_s[h];
        float dinv = 1.f/den_s[h];
        float acc = 0.f;
        for (int e=e0;e<e1;e++){
            int s = csr_src[e];
            float w = expf(lrelu(as2[s*NH2 + h] + adh)) * dinv;
            acc += w * h2[(size_t)s*F2 + t];
        }
        sacc[t] = acc;
    }
    __syncthreads();
    if (t < OUT_F){
        float v = (sacc[t] + sacc[t+32] + sacc[t+64] + sacc[t+96] + sacc[t+128]) * 0.2f + b2[t];
        x2[n*OUT_F + t] = v;
    }
}

// ---------------- bond scores + softmax over 64 bonds ----------------
__global__ __launch_bounds__(64) void k_bond(const float* __restrict__ x2,
        const int* __restrict__ lefts, const int* __restrict__ rights,
        float* __restrict__ out){
    int b = threadIdx.x;
    int L = lefts[b], R = rights[b];
    float s = 0.f;
    #pragma unroll
    for (int c=0;c<OUT_F;c+=4){
        float4 l4 = *(const float4*)(x2 + (size_t)L*OUT_F + c);
        float4 r4 = *(const float4*)(x2 + (size_t)R*OUT_F + c);
        s += l4.x+l4.y+l4.z+l4.w + r4.x+r4.y+r4.z+r4.w;
    }
    float m = s;
    #pragma unroll
    for (int off=1; off<64; off<<=1) m = fmaxf(m, __shfl_xor(m, off));
    float e = expf(s - m);
    float sum = e;
    #pragma unroll
    for (int off=1; off<64; off<<=1) sum += __shfl_xor(sum, off);
    out[b] = e / sum;
}

extern "C" void kernel_launch(void* const* d_in, const int* in_sizes, int n_in,
                              void* d_out, int out_size, void* d_ws, size_t ws_size,
                              hipStream_t stream){
    const float* x      = (const float*)d_in[0];
    const int*   ei     = (const int*)  d_in[1];
    const int*   lefts  = (const int*)  d_in[2];
    const int*   rights = (const int*)  d_in[3];
    const float* W1     = (const float*)d_in[4];
    const float* att_s1 = (const float*)d_in[5];
    const float* att_d1 = (const float*)d_in[6];
    const float* b1     = (const float*)d_in[7];
    const float* W2     = (const float*)d_in[8];
    const float* att_s2 = (const float*)d_in[9];
    const float* att_d2 = (const float*)d_in[10];
    const float* b2     = (const float*)d_in[11];
    float* out = (float*)d_out;

    // ---- choose chunk width from ws_size (same every call) ----
    // fixed bytes: partials + h2 + as1/ad1/dinv + as2/ad2 + x2 + vsT/vdT
    //            + bf16 planes (x, W1, W2) + CSR ints + slack
    size_t fixed = (size_t)(KS2*N_NODES*F2 + N_NODES*F2 + 3*N_NODES*NH1
                          + 2*N_NODES*NH2 + N_NODES*OUT_F + 2*IN_F*NH1
                          + 3*N_NODES + 1 + E_TOT) * 4
                 + (size_t)(2*N_NODES*IN_F + 2*F1*IN_F + 2*F2*F1) * 2
                 + 32768;
    int CF = 512;
    const int cands[2] = {2048, 1024};
    for (int c = 0; c < 2; c++){
        size_t need = fixed + (size_t)N_NODES * cands[c] * 4 * 2;  // h1c + x1c
        if (need <= ws_size){ CF = cands[c]; break; }
    }
    const int NCHUNK = F1 / CF;
    int chs = 0; while ((1 << chs) < CF/HID) chs++;

    char* ws = (char*)d_ws;
    size_t off = 0;
    auto alloc = [&](size_t bytes) -> void* {
        void* p = ws + off;
        off += (bytes + 255) & ~(size_t)255;
        return p;
    };
    float* h1c    = (float*)alloc((size_t)N_NODES*CF*4);
    float* x1c    = (float*)alloc((size_t)N_NODES*CF*4);
    float* part   = (float*)alloc((size_t)KS2*N_NODES*F2*4);
    float* h2     = (float*)alloc((size_t)N_NODES*F2*4);
    float* as1    = (float*)alloc((size_t)N_NODES*NH1*4);
    float* ad1    = (float*)alloc((size_t)N_NODES*NH1*4);
    float* dinv   = (float*)alloc((size_t)N_NODES*NH1*4);
    float* as2    = (float*)alloc((size_t)N_NODES*NH2*4);
    float* ad2    = (float*)alloc((size_t)N_NODES*NH2*4);
    float* x2     = (float*)alloc((size_t)N_NODES*OUT_F*4);
    float* vsT    = (float*)alloc((size_t)IN_F*NH1*4);
    float* vdT    = (float*)alloc((size_t)IN_F*NH1*4);
    unsigned short* xhi  = (unsigned short*)alloc((size_t)N_NODES*IN_F*2);
    unsigned short* xlo  = (unsigned short*)alloc((size_t)N_NODES*IN_F*2);
    unsigned short* w1hi = (unsigned short*)alloc((size_t)F1*IN_F*2);
    unsigned short* w1lo = (unsigned short*)alloc((size_t)F1*IN_F*2);
    unsigned short* w2hi = (unsigned short*)alloc((size_t)F2*F1*2);
    unsigned short* w2lo = (unsigned short*)alloc((size_t)F2*F1*2);
    int* counts    = (int*)alloc((size_t)N_NODES*4);
    int* row_start = (int*)alloc((size_t)(N_NODES+1)*4);
    int* cursor    = (int*)alloc((size_t)N_NODES*4);
    int* csr_src   = (int*)alloc((size_t)E_TOT*4);

    // CSR by destination
    k_init_counts<<<32, 256, 0, stream>>>(counts);
    k_count<<<192, 256, 0, stream>>>(ei, counts);
    k_scan<<<1, 1024, 0, stream>>>(counts, row_start, cursor);
    k_fill<<<224, 256, 0, stream>>>(ei, cursor, csr_src);

    // bf16 hi/lo planes for MFMA operands
    k_split<<<(N_NODES*IN_F+255)/256, 256, 0, stream>>>(x,  xhi,  xlo,  N_NODES*IN_F);
    k_split<<<(F1*IN_F+255)/256,      256, 0, stream>>>(W1, w1hi, w1lo, F1*IN_F);
    k_split<<<(F2*F1+255)/256,        256, 0, stream>>>(W2, w2hi, w2lo, F2*F1);

    // alpha dots + denominators (once, from x)
    k_attvec<<<NH1, 128, 0, stream>>>(W1, att_s1, att_d1, vsT, vdT);
    k_alpha1x<<<N_NODES, 128, 0, stream>>>(x, vsT, vdT, as1, ad1);
    k_dinv<<<N_NODES, 64, 0, stream>>>(as1, ad1, row_start, csr_src, dinv);

    // zero gemm2 partial accumulators
    k_zero<<<KS2*N_NODES*F2/4/256, 256, 0, stream>>>((float4*)part);

    for (int c = 0; c < NCHUNK; c++){
        int cb = c * CF;
        int h0 = cb / HID;
        k_gemm1<<<dim3(CF/128, 64), 256, 0, stream>>>(
            xhi, xlo, w1hi, w1lo, h1c, CF, cb);
        k_agg1<<<N_NODES, CF/8, 0, stream>>>(
            h1c, as1, ad1, dinv, row_start, csr_src, b1 + cb, x1c, CF, h0, chs);
        k_gemm2<<<dim3(128, KS2), 256, 0, stream>>>(
            x1c, w2hi, w2lo, part, CF, cb);
    }

    k_reduce<<<N_NODES*F2/4/256, 256, 0, stream>>>(part, h2);
    k_alpha2<<<N_NODES, 64, 0, stream>>>(h2, att_s2, att_d2, as2, ad2);
    k_agg2<<<N_NODES, 256, 0, stream>>>(h2, as2, ad2, row_start, csr_src, b2, x2);

    k_bond<<<1, 64, 0, stream>>>(x2, lefts, rights, out);
}